// Round 3
// baseline (612.658 us; speedup 1.0000x reference)
//
#include <hip/hip_runtime.h>
#include <hip/hip_bf16.h>
#include <stdint.h>

// Problem constants
#define TT 64
#define BB 128
#define OBSD 64
#define FOBS 120   // OBS_D + CAP_D
#define FC 128
#define G3 384
#define NS 8192    // T*B
#define DD 8
#define FF 64
#define HN 128
#define TGT 64
#define ADIM 5

__device__ __forceinline__ float sigmoidf_(float x) { return 1.0f / (1.0f + __expf(-x)); }
__device__ __forceinline__ float tanhf_(float x) {
    float e = __expf(-2.0f * fabsf(x));
    float r = (1.0f - e) / (1.0f + e);
    return copysignf(r, x);
}

// ---------------------------------------------------------------------------
// K1a: emb = relu(obs @ embed_w + embed_b)   (8192 x 64) @ (64 x 128)
// ---------------------------------------------------------------------------
__global__ __launch_bounds__(256) void k_embed(
    const float* __restrict__ fobs, const float* __restrict__ We,
    const float* __restrict__ be, float* __restrict__ emb)
{
    __shared__ float obs_t[64][68];
    __shared__ float W_t[64][128];
    int tid = threadIdx.x;
    int s0 = blockIdx.x * 64;
    {
        int rl = tid >> 4, e4 = tid & 15;
#pragma unroll
        for (int rr = 0; rr < 4; ++rr) {
            int r = rl + rr * 16;
            float4 v = *(const float4*)&fobs[(size_t)(s0 + r) * FOBS + e4 * 4];
            *(float4*)&obs_t[r][e4 * 4] = v;
        }
    }
#pragma unroll
    for (int i = 0; i < 8; ++i) {
        int idx = tid + i * 256;
        int e = idx >> 5, c4 = idx & 31;
        float4 v = *(const float4*)&We[(size_t)e * 128 + c4 * 4];
        *(float4*)&W_t[e][c4 * 4] = v;
    }
    __syncthreads();
    int c = tid & 127, half = tid >> 7;
    float acc[32];
    float bc = be[c];
#pragma unroll
    for (int k = 0; k < 32; ++k) acc[k] = bc;
#pragma unroll
    for (int e4 = 0; e4 < 16; ++e4) {
        float w0 = W_t[4 * e4 + 0][c], w1 = W_t[4 * e4 + 1][c];
        float w2 = W_t[4 * e4 + 2][c], w3 = W_t[4 * e4 + 3][c];
#pragma unroll
        for (int k = 0; k < 32; ++k) {
            float4 ov = *(const float4*)&obs_t[half * 32 + k][e4 * 4];
            acc[k] += ov.x * w0 + ov.y * w1 + ov.z * w2 + ov.w * w3;
        }
    }
#pragma unroll
    for (int k = 0; k < 32; ++k)
        emb[(size_t)(s0 + half * 32 + k) * FC + c] = fmaxf(acc[k], 0.0f);
}

// ---------------------------------------------------------------------------
// K1b: gi = emb @ gru_wi    (8192 x 128) @ (128 x 384)
// ---------------------------------------------------------------------------
__global__ __launch_bounds__(256) void k_gi(
    const float* __restrict__ emb, const float* __restrict__ Wi, float* __restrict__ gi)
{
    __shared__ float e_t[64][132];
    __shared__ float w_t[128 * 64];
    int tid = threadIdx.x;
    int st = blockIdx.x / 6, gt = blockIdx.x % 6;
    int s0 = st * 64, g0 = gt * 64;
#pragma unroll
    for (int i = 0; i < 8; ++i) {
        int idx = tid + i * 256;
        int r = idx >> 5, c4 = idx & 31;
        float4 v = *(const float4*)&emb[(size_t)(s0 + r) * FC + c4 * 4];
        *(float4*)&e_t[r][c4 * 4] = v;
    }
#pragma unroll
    for (int i = 0; i < 8; ++i) {
        int idx = tid + i * 256;
        int r = idx >> 4, g4 = idx & 15;
        float4 v = *(const float4*)&Wi[(size_t)r * G3 + g0 + g4 * 4];
        *(float4*)&w_t[r * 64 + g4 * 4] = v;
    }
    __syncthreads();
    int sb4 = (tid >> 4) * 4, ob4 = (tid & 15) * 4;
    float acc[4][4];
#pragma unroll
    for (int a = 0; a < 4; ++a)
#pragma unroll
        for (int b = 0; b < 4; ++b) acc[a][b] = 0.0f;
    for (int c4 = 0; c4 < 32; ++c4) {
        float4 e4[4], w4[4];
#pragma unroll
        for (int si = 0; si < 4; ++si) e4[si] = *(const float4*)&e_t[sb4 + si][c4 * 4];
#pragma unroll
        for (int cc = 0; cc < 4; ++cc) w4[cc] = *(const float4*)&w_t[(c4 * 4 + cc) * 64 + ob4];
#pragma unroll
        for (int si = 0; si < 4; ++si) {
            const float* ep = (const float*)&e4[si];
#pragma unroll
            for (int cc = 0; cc < 4; ++cc) {
                float ev = ep[cc];
                const float* wp = (const float*)&w4[cc];
                acc[si][0] += ev * wp[0];
                acc[si][1] += ev * wp[1];
                acc[si][2] += ev * wp[2];
                acc[si][3] += ev * wp[3];
            }
        }
    }
#pragma unroll
    for (int si = 0; si < 4; ++si) {
        float4 sv;
        sv.x = acc[si][0]; sv.y = acc[si][1]; sv.z = acc[si][2]; sv.w = acc[si][3];
        *(float4*)&gi[(size_t)(s0 + sb4 + si) * G3 + g0 + ob4] = sv;
    }
}

// ---------------------------------------------------------------------------
// K2: GRU scan. One WG per batch element.
// ---------------------------------------------------------------------------
__global__ __launch_bounds__(768) void k_gru(
    const float* __restrict__ gi, const float* __restrict__ Wh, const float* __restrict__ bh,
    const int* __restrict__ dones, const float* __restrict__ h0,
    float* __restrict__ emb_seq, float* __restrict__ hid_out)
{
    __shared__ float h_lds[128];
    __shared__ float gh_lds[384];
    int b = blockIdx.x, tid = threadIdx.x;
    int col = tid >> 1, half = tid & 1;
    float W[64];
#pragma unroll
    for (int i = 0; i < 64; ++i) W[i] = Wh[(size_t)(half * 64 + i) * G3 + col];
    float bias = bh[col];
    if (tid < 128) h_lds[tid] = h0[(size_t)b * FC + tid];
    __syncthreads();
    for (int t = 0; t < TT; ++t) {
        float hs = dones[t * BB + b] ? 0.0f : 1.0f;
        float d = 0.0f;
#pragma unroll
        for (int i4 = 0; i4 < 16; ++i4) {
            float4 h4 = *(const float4*)&h_lds[half * 64 + i4 * 4];
            d += W[i4 * 4 + 0] * h4.x + W[i4 * 4 + 1] * h4.y
               + W[i4 * 4 + 2] * h4.z + W[i4 * 4 + 3] * h4.w;
        }
        d *= hs;
        d += __shfl_xor(d, 1, 64);
        if (half == 0) gh_lds[col] = d + bias;
        __syncthreads();
        if (tid < 128) {
            int c = tid;
            const float* gr = gi + ((size_t)t * BB + b) * G3;
            float r = sigmoidf_(gr[c] + gh_lds[c]);
            float z = sigmoidf_(gr[128 + c] + gh_lds[128 + c]);
            float n = tanhf_(gr[256 + c] + r * gh_lds[256 + c]);
            float hnew = (1.0f - z) * n + z * (hs * h_lds[c]);
            h_lds[c] = hnew;
            emb_seq[((size_t)t * BB + b) * FC + c] = hnew;
        }
        __syncthreads();
    }
    if (tid < 128) hid_out[(size_t)b * FC + tid] = h_lds[tid];
}

// ---------------------------------------------------------------------------
// K3: tiny transformer on capability features.
// ---------------------------------------------------------------------------
__global__ __launch_bounds__(256) void k_attn(
    const float* __restrict__ fobs,
    const float* __restrict__ tWq, const float* __restrict__ tWk,
    const float* __restrict__ tWv, const float* __restrict__ tWo,
    const float* __restrict__ ln1s, const float* __restrict__ ln1b,
    const float* __restrict__ ffw1, const float* __restrict__ ffb1,
    const float* __restrict__ ffw2, const float* __restrict__ ffb2,
    const float* __restrict__ ln2s, const float* __restrict__ ln2b,
    float* __restrict__ cap_repr)
{
    __shared__ float wq[2][8][8], wk[2][8][8], wv[2][8][8], wo[2][8][8];
    __shared__ float l1s[2][8], l1b[2][8], l2s[2][8], l2b[2][8];
    __shared__ float f1[2][8][64], fb1[2][64];
    __shared__ float f2[2][64][8], fb2w[2][8];
    __shared__ float k_l[32][8][9], v_l[32][8][9];
    int tid = threadIdx.x;
    for (int i = tid; i < 128; i += 256) {
        ((float*)wq)[i] = tWq[i]; ((float*)wk)[i] = tWk[i];
        ((float*)wv)[i] = tWv[i]; ((float*)wo)[i] = tWo[i];
        ((float*)fb1)[i] = ffb1[i];
    }
    if (tid < 16) {
        ((float*)l1s)[tid] = ln1s[tid]; ((float*)l1b)[tid] = ln1b[tid];
        ((float*)l2s)[tid] = ln2s[tid]; ((float*)l2b)[tid] = ln2b[tid];
        ((float*)fb2w)[tid] = ffb2[tid];
    }
    for (int i = tid; i < 1024; i += 256) { ((float*)f1)[i] = ffw1[i]; ((float*)f2)[i] = ffw2[i]; }
    int sl = tid >> 3, a = tid & 7;
    int s = blockIdx.x * 32 + sl;
    float x[8];
#pragma unroll
    for (int i = 0; i < 7; ++i) x[i] = fobs[(size_t)s * FOBS + OBSD + a * 7 + i];
    x[7] = (a == 0) ? 1.0f : 0.0f;
    __syncthreads();
    for (int l = 0; l < 2; ++l) {
        float q[8], k[8], v[8];
#pragma unroll
        for (int d = 0; d < 8; ++d) { q[d] = 0.f; k[d] = 0.f; v[d] = 0.f; }
#pragma unroll
        for (int e = 0; e < 8; ++e) {
            float xe = x[e];
#pragma unroll
            for (int d = 0; d < 8; ++d) {
                q[d] += xe * wq[l][e][d];
                k[d] += xe * wk[l][e][d];
                v[d] += xe * wv[l][e][d];
            }
        }
#pragma unroll
        for (int d = 0; d < 8; ++d) { k_l[sl][a][d] = k[d]; v_l[sl][a][d] = v[d]; }
        __syncthreads();
        float o[8];
#pragma unroll
        for (int h = 0; h < 4; ++h) {
            float sc[8]; float mx = -1e30f;
#pragma unroll
            for (int ka = 0; ka < 8; ++ka) {
                float sv = (q[2 * h] * k_l[sl][ka][2 * h] + q[2 * h + 1] * k_l[sl][ka][2 * h + 1])
                           * 0.70710678118654752f;
                sc[ka] = sv; mx = fmaxf(mx, sv);
            }
            float ssum = 0.f;
#pragma unroll
            for (int ka = 0; ka < 8; ++ka) { sc[ka] = __expf(sc[ka] - mx); ssum += sc[ka]; }
            float inv = 1.0f / ssum;
            float o0 = 0.f, o1 = 0.f;
#pragma unroll
            for (int ka = 0; ka < 8; ++ka) {
                float at = sc[ka] * inv;
                o0 += at * v_l[sl][ka][2 * h];
                o1 += at * v_l[sl][ka][2 * h + 1];
            }
            o[2 * h] = o0; o[2 * h + 1] = o1;
        }
        float y[8];
#pragma unroll
        for (int e = 0; e < 8; ++e) y[e] = x[e];
#pragma unroll
        for (int d = 0; d < 8; ++d) {
            float od = o[d];
#pragma unroll
            for (int e = 0; e < 8; ++e) y[e] += od * wo[l][d][e];
        }
        {
            float m = 0.f;
#pragma unroll
            for (int e = 0; e < 8; ++e) m += y[e];
            m *= 0.125f;
            float vv = 0.f;
#pragma unroll
            for (int e = 0; e < 8; ++e) { float dd = y[e] - m; vv += dd * dd; }
            vv *= 0.125f;
            float rs = rsqrtf(vv + 1e-6f);
#pragma unroll
            for (int e = 0; e < 8; ++e)
                x[e] = 2.0f * ((y[e] - m) * rs * l1s[l][e] + l1b[l][e]);
        }
        float t1[64];
#pragma unroll
        for (int f = 0; f < 64; ++f) t1[f] = 0.f;
#pragma unroll
        for (int e = 0; e < 8; ++e) {
            float xe = x[e];
#pragma unroll
            for (int f = 0; f < 64; ++f) t1[f] += xe * f1[l][e][f];
        }
        float y2[8];
#pragma unroll
        for (int e = 0; e < 8; ++e) y2[e] = x[e] + fb2w[l][e];   // residual + ffb2
#pragma unroll
        for (int f = 0; f < 64; ++f) {
            float tf = fmaxf(t1[f] + fb1[l][f], 0.0f);
#pragma unroll
            for (int e = 0; e < 8; ++e) y2[e] += tf * f2[l][f][e];
        }
        {
            float m = 0.f;
#pragma unroll
            for (int e = 0; e < 8; ++e) m += y2[e];
            m *= 0.125f;
            float vv = 0.f;
#pragma unroll
            for (int e = 0; e < 8; ++e) { float dd = y2[e] - m; vv += dd * dd; }
            vv *= 0.125f;
            float rs = rsqrtf(vv + 1e-6f);
#pragma unroll
            for (int e = 0; e < 8; ++e)
                x[e] = 2.0f * ((y2[e] - m) * rs * l2s[l][e] + l2b[l][e]);
        }
        __syncthreads();
    }
#pragma unroll
    for (int e = 0; e < 8; ++e) {
        float xv = x[e];
        xv += __shfl_xor(xv, 1, 8);
        xv += __shfl_xor(xv, 2, 8);
        xv += __shfl_xor(xv, 4, 8);
        if (a == 0) cap_repr[(size_t)s * 8 + e] = xv * 0.125f;
    }
}

// ---------------------------------------------------------------------------
// K3b: hypernet first layers + small second layers.
// ---------------------------------------------------------------------------
__global__ __launch_bounds__(256) void k_hyper(
    const float* __restrict__ cap_repr, const float* __restrict__ emb_seq,
    const float* __restrict__ hw1_1, const float* __restrict__ hb1_1,
    const float* __restrict__ hw1_2, const float* __restrict__ hb1_2,
    const float* __restrict__ hw1_3, const float* __restrict__ hb1_3,
    const float* __restrict__ hw1_4, const float* __restrict__ hb1_4,
    const float* __restrict__ hb2_1,
    const float* __restrict__ hw2_2, const float* __restrict__ hb2_2,
    const float* __restrict__ hw2_3, const float* __restrict__ hb2_3,
    const float* __restrict__ hw2_4, const float* __restrict__ hb2_4,
    float* __restrict__ hh1g, float* __restrict__ b1eff,
    float* __restrict__ w2h, float* __restrict__ b2h)
{
    __shared__ float cr[16][8];
    __shared__ float hh[4][16][132];
    __shared__ float es[16][132];
    int tid = threadIdx.x;
    int s0 = blockIdx.x * 16;
    if (tid < 128) ((float*)cr)[tid] = cap_repr[(size_t)s0 * 8 + tid];
#pragma unroll
    for (int i = 0; i < 2; ++i) {
        int idx = tid + i * 256;
        int r = idx >> 5, c4 = idx & 31;
        float4 v = *(const float4*)&emb_seq[(size_t)(s0 + r) * FC + c4 * 4];
        *(float4*)&es[r][c4 * 4] = v;
    }
    __syncthreads();
#pragma unroll
    for (int it = 0; it < 32; ++it) {
        int idx = tid + it * 256;
        int u = idx & 127;
        int sn = (idx >> 7) & 15;
        int n = idx >> 11;
        const float* w = (n == 0) ? hw1_1 : ((n == 1) ? hw1_2 : ((n == 2) ? hw1_3 : hw1_4));
        const float* bb = (n == 0) ? hb1_1 : ((n == 1) ? hb1_2 : ((n == 2) ? hb1_3 : hb1_4));
        float acc = bb[u];
#pragma unroll
        for (int e = 0; e < 8; ++e) acc += cr[sn][e] * w[e * 128 + u];
        acc = fmaxf(acc, 0.0f);
        hh[n][sn][u] = acc;
        if (n == 0) hh1g[(size_t)(s0 + sn) * 128 + u] = acc;
    }
    __syncthreads();
#pragma unroll
    for (int it = 0; it < 4; ++it) {
        int idx = tid + it * 256;
        int o = idx & 63, sn = idx >> 6;
        float acc = hb2_2[o];
        for (int j = 0; j < 128; ++j) acc += hh[1][sn][j] * hw2_2[j * 64 + o];
        for (int c = 0; c < 128; ++c) acc += es[sn][c] * hb2_1[c * 64 + o];
        b1eff[(size_t)(s0 + sn) * 64 + o] = acc;
    }
    for (int it = 0; it < 2; ++it) {
        int oa = tid + it * 256;
        if (oa < 320) {
            float acc[16];
#pragma unroll
            for (int sn = 0; sn < 16; ++sn) acc[sn] = 0.f;
            for (int j = 0; j < 128; ++j) {
                float w = hw2_3[j * 320 + oa];
#pragma unroll
                for (int sn = 0; sn < 16; ++sn) acc[sn] += hh[2][sn][j] * w;
            }
            float bb = hb2_3[oa];
#pragma unroll
            for (int sn = 0; sn < 16; ++sn) w2h[(size_t)(s0 + sn) * 320 + oa] = acc[sn] + bb;
        }
    }
    if (tid < 80) {
        int aa = tid % 5, sn = tid / 5;
        float acc = hb2_4[aa];
        for (int j = 0; j < 128; ++j) acc += hh[3][sn][j] * hw2_4[j * 5 + aa];
        b2h[(size_t)(s0 + sn) * 5 + aa] = acc;
    }
}

// ---------------------------------------------------------------------------
// K4: big fused GEMM.  out[s,o] = sum_{j,c} hh1[s,j]*emb_seq[s,c]*W[j,c*64+o]
// M=8192, N=64, K=16384. Split-K=4 (j-quarters), 64-sample M-tiles.
// Per-thread tile: 2 samples x 8 outputs (32x8 thread grid) -> 89% FMA density
// (was 4x4 -> 80%). W row staged per-j (32 KB) with 1-deep register prefetch.
// ---------------------------------------------------------------------------
__global__ __launch_bounds__(256) void k_bigmm(
    const float* __restrict__ emb_seq, const float* __restrict__ hh1g,
    const float* __restrict__ W2big, float* __restrict__ partials)
{
    __shared__ float e_t[64][132];
    __shared__ float h_t[64][36];
    __shared__ float w_t[128 * 64];
    int tid = threadIdx.x;
    int mt = blockIdx.x >> 2, ks = blockIdx.x & 3;
    int s0 = mt * 64, j0 = ks * 32;
#pragma unroll
    for (int i = 0; i < 8; ++i) {
        int idx = tid + i * 256;
        int r = idx >> 5, c4 = idx & 31;
        float4 v = *(const float4*)&emb_seq[(size_t)(s0 + r) * FC + c4 * 4];
        *(float4*)&e_t[r][c4 * 4] = v;
    }
#pragma unroll
    for (int i = 0; i < 2; ++i) {
        int idx = tid + i * 256;
        int r = idx >> 3, j4 = idx & 7;
        float4 v = *(const float4*)&hh1g[(size_t)(s0 + r) * 128 + j0 + j4 * 4];
        *(float4*)&h_t[r][j4 * 4] = v;
    }
    const float* Wbase = W2big + (size_t)j0 * 8192;
    float4 wreg[8];
#pragma unroll
    for (int i = 0; i < 8; ++i) wreg[i] = *(const float4*)&Wbase[(size_t)(tid + i * 256) * 4];

    int sg = tid >> 3;           // 0..31  -> samples sg*2, sg*2+1
    int og8 = (tid & 7) * 8;     // 0..56  -> outputs og8..og8+7
    int s2 = sg * 2;
    float acc[2][8];
#pragma unroll
    for (int a = 0; a < 2; ++a)
#pragma unroll
        for (int b = 0; b < 8; ++b) acc[a][b] = 0.0f;

    for (int jj = 0; jj < 32; ++jj) {
        __syncthreads();
#pragma unroll
        for (int i = 0; i < 8; ++i) *(float4*)&w_t[(tid + i * 256) * 4] = wreg[i];
        if (jj < 31) {
            const float* Wn = Wbase + (size_t)(jj + 1) * 8192;
#pragma unroll
            for (int i = 0; i < 8; ++i) wreg[i] = *(const float4*)&Wn[(size_t)(tid + i * 256) * 4];
        }
        __syncthreads();
        float hj0 = h_t[s2][jj], hj1 = h_t[s2 + 1][jj];
        for (int c4 = 0; c4 < 32; ++c4) {
            float4 e0 = *(const float4*)&e_t[s2][c4 * 4];
            float4 e1 = *(const float4*)&e_t[s2 + 1][c4 * 4];
            const float* e0p = (const float*)&e0;
            const float* e1p = (const float*)&e1;
#pragma unroll
            for (int cc = 0; cc < 4; ++cc) {
                const float* wp = &w_t[(c4 * 4 + cc) * 64 + og8];
                float4 wa = *(const float4*)&wp[0];
                float4 wb = *(const float4*)&wp[4];
                const float* wap = (const float*)&wa;
                const float* wbp = (const float*)&wb;
                float ae0 = hj0 * e0p[cc];
                float ae1 = hj1 * e1p[cc];
#pragma unroll
                for (int o = 0; o < 4; ++o) {
                    acc[0][o]     += ae0 * wap[o];
                    acc[0][o + 4] += ae0 * wbp[o];
                    acc[1][o]     += ae1 * wap[o];
                    acc[1][o + 4] += ae1 * wbp[o];
                }
            }
        }
    }
#pragma unroll
    for (int si = 0; si < 2; ++si) {
        float4 v0, v1;
        v0.x = acc[si][0]; v0.y = acc[si][1]; v0.z = acc[si][2]; v0.w = acc[si][3];
        v1.x = acc[si][4]; v1.y = acc[si][5]; v1.z = acc[si][6]; v1.w = acc[si][7];
        float* dst = &partials[(size_t)ks * (NS * 64) + (size_t)(s0 + s2 + si) * 64 + og8];
        *(float4*)&dst[0] = v0;
        *(float4*)&dst[4] = v1;
    }
}

// ---------------------------------------------------------------------------
// K5: epilogue. h1 = relu(sum_k partials + b1eff); logits = h1@w2 + b2.
// ---------------------------------------------------------------------------
__global__ __launch_bounds__(256) void k_final(
    const float* __restrict__ partials, const float* __restrict__ b1eff,
    const float* __restrict__ w2h, const float* __restrict__ b2h, float* __restrict__ out)
{
    int tid = threadIdx.x;
    int wv = tid >> 6, lane = tid & 63;
    int s = blockIdx.x * 4 + wv;
    float h1 = b1eff[(size_t)s * 64 + lane];
#pragma unroll
    for (int ks = 0; ks < 4; ++ks) h1 += partials[(size_t)ks * (NS * 64) + (size_t)s * 64 + lane];
    h1 = fmaxf(h1, 0.0f);
    float lg[5];
#pragma unroll
    for (int aa = 0; aa < 5; ++aa) lg[aa] = h1 * w2h[(size_t)s * 320 + lane * 5 + aa];
#pragma unroll
    for (int off = 32; off >= 1; off >>= 1) {
#pragma unroll
        for (int aa = 0; aa < 5; ++aa) lg[aa] += __shfl_xor(lg[aa], off, 64);
    }
    if (lane == 0) {
#pragma unroll
        for (int aa = 0; aa < 5; ++aa)
            out[16384 + (size_t)s * 5 + aa] = lg[aa] + b2h[(size_t)s * 5 + aa];
    }
}

// ---------------------------------------------------------------------------
extern "C" void kernel_launch(void* const* d_in, const int* in_sizes, int n_in,
                              void* d_out, int out_size, void* d_ws, size_t ws_size,
                              hipStream_t stream)
{
    (void)in_sizes; (void)n_in; (void)out_size; (void)ws_size;
    const float* hidden  = (const float*)d_in[0];
    const float* fobs    = (const float*)d_in[1];
    const int*   dones   = (const int*)d_in[2];
    const float* embed_w = (const float*)d_in[3];
    const float* embed_b = (const float*)d_in[4];
    const float* gru_wi  = (const float*)d_in[5];
    const float* gru_wh  = (const float*)d_in[6];
    const float* gru_bh  = (const float*)d_in[7];
    const float* tWq  = (const float*)d_in[8];
    const float* tWk  = (const float*)d_in[9];
    const float* tWv  = (const float*)d_in[10];
    const float* tWo  = (const float*)d_in[11];
    const float* ln1s = (const float*)d_in[12];
    const float* ln1b = (const float*)d_in[13];
    const float* ffw1 = (const float*)d_in[14];
    const float* ffb1 = (const float*)d_in[15];
    const float* ffw2 = (const float*)d_in[16];
    const float* ffb2 = (const float*)d_in[17];
    const float* ln2s = (const float*)d_in[18];
    const float* ln2b = (const float*)d_in[19];
    const float* hw1_1 = (const float*)d_in[20]; const float* hb1_1 = (const float*)d_in[21];
    const float* hw2_1 = (const float*)d_in[22]; const float* hb2_1 = (const float*)d_in[23];
    const float* hw1_2 = (const float*)d_in[24]; const float* hb1_2 = (const float*)d_in[25];
    const float* hw2_2 = (const float*)d_in[26]; const float* hb2_2 = (const float*)d_in[27];
    const float* hw1_3 = (const float*)d_in[28]; const float* hb1_3 = (const float*)d_in[29];
    const float* hw2_3 = (const float*)d_in[30]; const float* hb2_3 = (const float*)d_in[31];
    const float* hw1_4 = (const float*)d_in[32]; const float* hb1_4 = (const float*)d_in[33];
    const float* hw2_4 = (const float*)d_in[34]; const float* hb2_4 = (const float*)d_in[35];
    float* out = (float*)d_out;
    float* ws  = (float*)d_ws;

    // workspace layout (floats); parts overlays gi (dead after k_gru).
    float* gi      = ws;                      // 8192*384 (12 MB; dead after k_gru)
    float* parts   = ws;                      // 4*8192*64 (8 MB) — aliases gi
    float* emb     = gi      + 3145728;       // 8192*128
    float* emb_seq = emb     + 1048576;       // 8192*128
    float* cap_rep = emb_seq + 1048576;       // 8192*8
    float* hh1g    = cap_rep + 65536;         // 8192*128
    float* b1eff_  = hh1g    + 1048576;       // 8192*64
    float* w2hb    = b1eff_  + 524288;        // 8192*320
    float* b2hb    = w2hb    + 2621440;       // 8192*5

    k_embed<<<128, 256, 0, stream>>>(fobs, embed_w, embed_b, emb);
    k_gi<<<768, 256, 0, stream>>>(emb, gru_wi, gi);
    k_gru<<<128, 768, 0, stream>>>(gi, gru_wh, gru_bh, dones, hidden, emb_seq, out);
    k_attn<<<256, 256, 0, stream>>>(fobs, tWq, tWk, tWv, tWo, ln1s, ln1b,
                                    ffw1, ffb1, ffw2, ffb2, ln2s, ln2b, cap_rep);
    k_hyper<<<512, 256, 0, stream>>>(cap_rep, emb_seq,
                                     hw1_1, hb1_1, hw1_2, hb1_2, hw1_3, hb1_3, hw1_4, hb1_4,
                                     hb2_1, hw2_2, hb2_2, hw2_3, hb2_3, hw2_4, hb2_4,
                                     hh1g, b1eff_, w2hb, b2hb);
    k_bigmm<<<512, 256, 0, stream>>>(emb_seq, hh1g, hw2_1, parts);
    k_final<<<2048, 256, 0, stream>>>(parts, b1eff_, w2hb, b2hb, out);
}

// Round 5
// 405.913 us; speedup vs baseline: 1.5093x; 1.5093x over previous
//
#include <hip/hip_runtime.h>
#include <hip/hip_bf16.h>
#include <stdint.h>

// Problem constants
#define TT 64
#define BB 128
#define OBSD 64
#define FOBS 120   // OBS_D + CAP_D
#define FC 128
#define G3 384
#define NS 8192    // T*B
#define DD 8
#define FF 64
#define HN 128
#define TGT 64
#define ADIM 5

typedef __attribute__((ext_vector_type(8))) short bf16x8;
typedef __attribute__((ext_vector_type(4))) float f32x4;

__device__ __forceinline__ float sigmoidf_(float x) { return 1.0f / (1.0f + __expf(-x)); }
__device__ __forceinline__ float tanhf_(float x) {
    float e = __expf(-2.0f * fabsf(x));
    float r = (1.0f - e) / (1.0f + e);
    return copysignf(r, x);
}
__device__ __forceinline__ unsigned short f2bf_rne(float x) {
    unsigned u = __float_as_uint(x);
    return (unsigned short)((u + 0x7fffu + ((u >> 16) & 1u)) >> 16);
}

// ---------------------------------------------------------------------------
// K1a: emb = relu(obs @ embed_w + embed_b)   (8192 x 64) @ (64 x 128)
// ---------------------------------------------------------------------------
__global__ __launch_bounds__(256) void k_embed(
    const float* __restrict__ fobs, const float* __restrict__ We,
    const float* __restrict__ be, float* __restrict__ emb)
{
    __shared__ float obs_t[64][68];
    __shared__ float W_t[64][128];
    int tid = threadIdx.x;
    int s0 = blockIdx.x * 64;
    {
        int rl = tid >> 4, e4 = tid & 15;
#pragma unroll
        for (int rr = 0; rr < 4; ++rr) {
            int r = rl + rr * 16;
            float4 v = *(const float4*)&fobs[(size_t)(s0 + r) * FOBS + e4 * 4];
            *(float4*)&obs_t[r][e4 * 4] = v;
        }
    }
#pragma unroll
    for (int i = 0; i < 8; ++i) {
        int idx = tid + i * 256;
        int e = idx >> 5, c4 = idx & 31;
        float4 v = *(const float4*)&We[(size_t)e * 128 + c4 * 4];
        *(float4*)&W_t[e][c4 * 4] = v;
    }
    __syncthreads();
    int c = tid & 127, half = tid >> 7;
    float acc[32];
    float bc = be[c];
#pragma unroll
    for (int k = 0; k < 32; ++k) acc[k] = bc;
#pragma unroll
    for (int e4 = 0; e4 < 16; ++e4) {
        float w0 = W_t[4 * e4 + 0][c], w1 = W_t[4 * e4 + 1][c];
        float w2 = W_t[4 * e4 + 2][c], w3 = W_t[4 * e4 + 3][c];
#pragma unroll
        for (int k = 0; k < 32; ++k) {
            float4 ov = *(const float4*)&obs_t[half * 32 + k][e4 * 4];
            acc[k] += ov.x * w0 + ov.y * w1 + ov.z * w2 + ov.w * w3;
        }
    }
#pragma unroll
    for (int k = 0; k < 32; ++k)
        emb[(size_t)(s0 + half * 32 + k) * FC + c] = fmaxf(acc[k], 0.0f);
}

// ---------------------------------------------------------------------------
// K1b: gi = emb @ gru_wi    (8192 x 128) @ (128 x 384)
// ---------------------------------------------------------------------------
__global__ __launch_bounds__(256) void k_gi(
    const float* __restrict__ emb, const float* __restrict__ Wi, float* __restrict__ gi)
{
    __shared__ float e_t[64][132];
    __shared__ float w_t[128 * 64];
    int tid = threadIdx.x;
    int st = blockIdx.x / 6, gt = blockIdx.x % 6;
    int s0 = st * 64, g0 = gt * 64;
#pragma unroll
    for (int i = 0; i < 8; ++i) {
        int idx = tid + i * 256;
        int r = idx >> 5, c4 = idx & 31;
        float4 v = *(const float4*)&emb[(size_t)(s0 + r) * FC + c4 * 4];
        *(float4*)&e_t[r][c4 * 4] = v;
    }
#pragma unroll
    for (int i = 0; i < 8; ++i) {
        int idx = tid + i * 256;
        int r = idx >> 4, g4 = idx & 15;
        float4 v = *(const float4*)&Wi[(size_t)r * G3 + g0 + g4 * 4];
        *(float4*)&w_t[r * 64 + g4 * 4] = v;
    }
    __syncthreads();
    int sb4 = (tid >> 4) * 4, ob4 = (tid & 15) * 4;
    float acc[4][4];
#pragma unroll
    for (int a = 0; a < 4; ++a)
#pragma unroll
        for (int b = 0; b < 4; ++b) acc[a][b] = 0.0f;
    for (int c4 = 0; c4 < 32; ++c4) {
        float4 e4[4], w4[4];
#pragma unroll
        for (int si = 0; si < 4; ++si) e4[si] = *(const float4*)&e_t[sb4 + si][c4 * 4];
#pragma unroll
        for (int cc = 0; cc < 4; ++cc) w4[cc] = *(const float4*)&w_t[(c4 * 4 + cc) * 64 + ob4];
#pragma unroll
        for (int si = 0; si < 4; ++si) {
            const float* ep = (const float*)&e4[si];
#pragma unroll
            for (int cc = 0; cc < 4; ++cc) {
                float ev = ep[cc];
                const float* wp = (const float*)&w4[cc];
                acc[si][0] += ev * wp[0];
                acc[si][1] += ev * wp[1];
                acc[si][2] += ev * wp[2];
                acc[si][3] += ev * wp[3];
            }
        }
    }
#pragma unroll
    for (int si = 0; si < 4; ++si) {
        float4 sv;
        sv.x = acc[si][0]; sv.y = acc[si][1]; sv.z = acc[si][2]; sv.w = acc[si][3];
        *(float4*)&gi[(size_t)(s0 + sb4 + si) * G3 + g0 + ob4] = sv;
    }
}

// ---------------------------------------------------------------------------
// K1c: pre-swizzle hw2_1 into bf16 MFMA B-fragment order.
// B[k][o], k=j*128+c (16384 x 64).  Fragment (j,ks,nt): 64 lanes x 8 bf16,
// element (lane,i) = B[j*128 + ks*32 + (lane>>4)*8 + i][nt*16 + (lane&15)].
// ---------------------------------------------------------------------------
__global__ __launch_bounds__(256) void k_prepW(
    const float* __restrict__ W, unsigned short* __restrict__ W_swz)
{
    int fid = blockIdx.x * 256 + threadIdx.x;       // 0..131071 fragment-lane id
    int lane = fid & 63;
    int nt = (fid >> 6) & 3;
    int ks = (fid >> 8) & 3;
    int j  = fid >> 10;
    int col = nt * 16 + (lane & 15);
    int kbase = ks * 32 + ((lane >> 4) * 8);
    const float* src = W + ((size_t)j * 128 + kbase) * 64 + col;
    unsigned short o[8];
#pragma unroll
    for (int i = 0; i < 8; ++i) o[i] = f2bf_rne(src[(size_t)i * 64]);
    *(uint4*)&W_swz[(size_t)fid * 8] = *(const uint4*)o;
}

// ---------------------------------------------------------------------------
// K2: GRU scan. One WG per batch element. Also emits bf16 copy of emb_seq.
// ---------------------------------------------------------------------------
__global__ __launch_bounds__(768) void k_gru(
    const float* __restrict__ gi, const float* __restrict__ Wh, const float* __restrict__ bh,
    const int* __restrict__ dones, const float* __restrict__ h0,
    float* __restrict__ emb_seq, unsigned short* __restrict__ embb,
    float* __restrict__ hid_out)
{
    __shared__ float h_lds[128];
    __shared__ float gh_lds[384];
    int b = blockIdx.x, tid = threadIdx.x;
    int col = tid >> 1, half = tid & 1;
    float W[64];
#pragma unroll
    for (int i = 0; i < 64; ++i) W[i] = Wh[(size_t)(half * 64 + i) * G3 + col];
    float bias = bh[col];
    if (tid < 128) h_lds[tid] = h0[(size_t)b * FC + tid];
    __syncthreads();
    for (int t = 0; t < TT; ++t) {
        float hs = dones[t * BB + b] ? 0.0f : 1.0f;
        float d = 0.0f;
#pragma unroll
        for (int i4 = 0; i4 < 16; ++i4) {
            float4 h4 = *(const float4*)&h_lds[half * 64 + i4 * 4];
            d += W[i4 * 4 + 0] * h4.x + W[i4 * 4 + 1] * h4.y
               + W[i4 * 4 + 2] * h4.z + W[i4 * 4 + 3] * h4.w;
        }
        d *= hs;
        d += __shfl_xor(d, 1, 64);
        if (half == 0) gh_lds[col] = d + bias;
        __syncthreads();
        if (tid < 128) {
            int c = tid;
            const float* gr = gi + ((size_t)t * BB + b) * G3;
            float r = sigmoidf_(gr[c] + gh_lds[c]);
            float z = sigmoidf_(gr[128 + c] + gh_lds[128 + c]);
            float n = tanhf_(gr[256 + c] + r * gh_lds[256 + c]);
            float hnew = (1.0f - z) * n + z * (hs * h_lds[c]);
            h_lds[c] = hnew;
            emb_seq[((size_t)t * BB + b) * FC + c] = hnew;
            embb[((size_t)t * BB + b) * FC + c] = f2bf_rne(hnew);
        }
        __syncthreads();
    }
    if (tid < 128) hid_out[(size_t)b * FC + tid] = h_lds[tid];
}

// ---------------------------------------------------------------------------
// K3: tiny transformer on capability features.
// ---------------------------------------------------------------------------
__global__ __launch_bounds__(256) void k_attn(
    const float* __restrict__ fobs,
    const float* __restrict__ tWq, const float* __restrict__ tWk,
    const float* __restrict__ tWv, const float* __restrict__ tWo,
    const float* __restrict__ ln1s, const float* __restrict__ ln1b,
    const float* __restrict__ ffw1, const float* __restrict__ ffb1,
    const float* __restrict__ ffw2, const float* __restrict__ ffb2,
    const float* __restrict__ ln2s, const float* __restrict__ ln2b,
    float* __restrict__ cap_repr)
{
    __shared__ float wq[2][8][8], wk[2][8][8], wv[2][8][8], wo[2][8][8];
    __shared__ float l1s[2][8], l1b[2][8], l2s[2][8], l2b[2][8];
    __shared__ float f1[2][8][64], fb1[2][64];
    __shared__ float f2[2][64][8], fb2w[2][8];
    __shared__ float k_l[32][8][9], v_l[32][8][9];
    int tid = threadIdx.x;
    for (int i = tid; i < 128; i += 256) {
        ((float*)wq)[i] = tWq[i]; ((float*)wk)[i] = tWk[i];
        ((float*)wv)[i] = tWv[i]; ((float*)wo)[i] = tWo[i];
        ((float*)fb1)[i] = ffb1[i];
    }
    if (tid < 16) {
        ((float*)l1s)[tid] = ln1s[tid]; ((float*)l1b)[tid] = ln1b[tid];
        ((float*)l2s)[tid] = ln2s[tid]; ((float*)l2b)[tid] = ln2b[tid];
        ((float*)fb2w)[tid] = ffb2[tid];
    }
    for (int i = tid; i < 1024; i += 256) { ((float*)f1)[i] = ffw1[i]; ((float*)f2)[i] = ffw2[i]; }
    int sl = tid >> 3, a = tid & 7;
    int s = blockIdx.x * 32 + sl;
    float x[8];
#pragma unroll
    for (int i = 0; i < 7; ++i) x[i] = fobs[(size_t)s * FOBS + OBSD + a * 7 + i];
    x[7] = (a == 0) ? 1.0f : 0.0f;
    __syncthreads();
    for (int l = 0; l < 2; ++l) {
        float q[8], k[8], v[8];
#pragma unroll
        for (int d = 0; d < 8; ++d) { q[d] = 0.f; k[d] = 0.f; v[d] = 0.f; }
#pragma unroll
        for (int e = 0; e < 8; ++e) {
            float xe = x[e];
#pragma unroll
            for (int d = 0; d < 8; ++d) {
                q[d] += xe * wq[l][e][d];
                k[d] += xe * wk[l][e][d];
                v[d] += xe * wv[l][e][d];
            }
        }
#pragma unroll
        for (int d = 0; d < 8; ++d) { k_l[sl][a][d] = k[d]; v_l[sl][a][d] = v[d]; }
        __syncthreads();
        float o[8];
#pragma unroll
        for (int h = 0; h < 4; ++h) {
            float sc[8]; float mx = -1e30f;
#pragma unroll
            for (int ka = 0; ka < 8; ++ka) {
                float sv = (q[2 * h] * k_l[sl][ka][2 * h] + q[2 * h + 1] * k_l[sl][ka][2 * h + 1])
                           * 0.70710678118654752f;
                sc[ka] = sv; mx = fmaxf(mx, sv);
            }
            float ssum = 0.f;
#pragma unroll
            for (int ka = 0; ka < 8; ++ka) { sc[ka] = __expf(sc[ka] - mx); ssum += sc[ka]; }
            float inv = 1.0f / ssum;
            float o0 = 0.f, o1 = 0.f;
#pragma unroll
            for (int ka = 0; ka < 8; ++ka) {
                float at = sc[ka] * inv;
                o0 += at * v_l[sl][ka][2 * h];
                o1 += at * v_l[sl][ka][2 * h + 1];
            }
            o[2 * h] = o0; o[2 * h + 1] = o1;
        }
        float y[8];
#pragma unroll
        for (int e = 0; e < 8; ++e) y[e] = x[e];
#pragma unroll
        for (int d = 0; d < 8; ++d) {
            float od = o[d];
#pragma unroll
            for (int e = 0; e < 8; ++e) y[e] += od * wo[l][d][e];
        }
        {
            float m = 0.f;
#pragma unroll
            for (int e = 0; e < 8; ++e) m += y[e];
            m *= 0.125f;
            float vv = 0.f;
#pragma unroll
            for (int e = 0; e < 8; ++e) { float dd = y[e] - m; vv += dd * dd; }
            vv *= 0.125f;
            float rs = rsqrtf(vv + 1e-6f);
#pragma unroll
            for (int e = 0; e < 8; ++e)
                x[e] = 2.0f * ((y[e] - m) * rs * l1s[l][e] + l1b[l][e]);
        }
        float t1[64];
#pragma unroll
        for (int f = 0; f < 64; ++f) t1[f] = 0.f;
#pragma unroll
        for (int e = 0; e < 8; ++e) {
            float xe = x[e];
#pragma unroll
            for (int f = 0; f < 64; ++f) t1[f] += xe * f1[l][e][f];
        }
        float y2[8];
#pragma unroll
        for (int e = 0; e < 8; ++e) y2[e] = x[e] + fb2w[l][e];   // residual + ffb2
#pragma unroll
        for (int f = 0; f < 64; ++f) {
            float tf = fmaxf(t1[f] + fb1[l][f], 0.0f);
#pragma unroll
            for (int e = 0; e < 8; ++e) y2[e] += tf * f2[l][f][e];
        }
        {
            float m = 0.f;
#pragma unroll
            for (int e = 0; e < 8; ++e) m += y2[e];
            m *= 0.125f;
            float vv = 0.f;
#pragma unroll
            for (int e = 0; e < 8; ++e) { float dd = y2[e] - m; vv += dd * dd; }
            vv *= 0.125f;
            float rs = rsqrtf(vv + 1e-6f);
#pragma unroll
            for (int e = 0; e < 8; ++e)
                x[e] = 2.0f * ((y2[e] - m) * rs * l2s[l][e] + l2b[l][e]);
        }
        __syncthreads();
    }
#pragma unroll
    for (int e = 0; e < 8; ++e) {
        float xv = x[e];
        xv += __shfl_xor(xv, 1, 8);
        xv += __shfl_xor(xv, 2, 8);
        xv += __shfl_xor(xv, 4, 8);
        if (a == 0) cap_repr[(size_t)s * 8 + e] = xv * 0.125f;
    }
}

// ---------------------------------------------------------------------------
// K3b: hypernet first layers + small second layers.
// ---------------------------------------------------------------------------
__global__ __launch_bounds__(256) void k_hyper(
    const float* __restrict__ cap_repr, const float* __restrict__ emb_seq,
    const float* __restrict__ hw1_1, const float* __restrict__ hb1_1,
    const float* __restrict__ hw1_2, const float* __restrict__ hb1_2,
    const float* __restrict__ hw1_3, const float* __restrict__ hb1_3,
    const float* __restrict__ hw1_4, const float* __restrict__ hb1_4,
    const float* __restrict__ hb2_1,
    const float* __restrict__ hw2_2, const float* __restrict__ hb2_2,
    const float* __restrict__ hw2_3, const float* __restrict__ hb2_3,
    const float* __restrict__ hw2_4, const float* __restrict__ hb2_4,
    float* __restrict__ hh1g, float* __restrict__ b1eff,
    float* __restrict__ w2h, float* __restrict__ b2h)
{
    __shared__ float cr[16][8];
    __shared__ float hh[4][16][132];
    __shared__ float es[16][132];
    int tid = threadIdx.x;
    int s0 = blockIdx.x * 16;
    if (tid < 128) ((float*)cr)[tid] = cap_repr[(size_t)s0 * 8 + tid];
#pragma unroll
    for (int i = 0; i < 2; ++i) {
        int idx = tid + i * 256;
        int r = idx >> 5, c4 = idx & 31;
        float4 v = *(const float4*)&emb_seq[(size_t)(s0 + r) * FC + c4 * 4];
        *(float4*)&es[r][c4 * 4] = v;
    }
    __syncthreads();
#pragma unroll
    for (int it = 0; it < 32; ++it) {
        int idx = tid + it * 256;
        int u = idx & 127;
        int sn = (idx >> 7) & 15;
        int n = idx >> 11;
        const float* w = (n == 0) ? hw1_1 : ((n == 1) ? hw1_2 : ((n == 2) ? hw1_3 : hw1_4));
        const float* bb = (n == 0) ? hb1_1 : ((n == 1) ? hb1_2 : ((n == 2) ? hb1_3 : hb1_4));
        float acc = bb[u];
#pragma unroll
        for (int e = 0; e < 8; ++e) acc += cr[sn][e] * w[e * 128 + u];
        acc = fmaxf(acc, 0.0f);
        hh[n][sn][u] = acc;
        if (n == 0) hh1g[(size_t)(s0 + sn) * 128 + u] = acc;
    }
    __syncthreads();
#pragma unroll
    for (int it = 0; it < 4; ++it) {
        int idx = tid + it * 256;
        int o = idx & 63, sn = idx >> 6;
        float acc = hb2_2[o];
        for (int j = 0; j < 128; ++j) acc += hh[1][sn][j] * hw2_2[j * 64 + o];
        for (int c = 0; c < 128; ++c) acc += es[sn][c] * hb2_1[c * 64 + o];
        b1eff[(size_t)(s0 + sn) * 64 + o] = acc;
    }
    for (int it = 0; it < 2; ++it) {
        int oa = tid + it * 256;
        if (oa < 320) {
            float acc[16];
#pragma unroll
            for (int sn = 0; sn < 16; ++sn) acc[sn] = 0.f;
            for (int j = 0; j < 128; ++j) {
                float w = hw2_3[j * 320 + oa];
#pragma unroll
                for (int sn = 0; sn < 16; ++sn) acc[sn] += hh[2][sn][j] * w;
            }
            float bb = hb2_3[oa];
#pragma unroll
            for (int sn = 0; sn < 16; ++sn) w2h[(size_t)(s0 + sn) * 320 + oa] = acc[sn] + bb;
        }
    }
    if (tid < 80) {
        int aa = tid % 5, sn = tid / 5;
        float acc = hb2_4[aa];
        for (int j = 0; j < 128; ++j) acc += hh[3][sn][j] * hw2_4[j * 5 + aa];
        b2h[(size_t)(s0 + sn) * 5 + aa] = acc;
    }
}

// ---------------------------------------------------------------------------
// K4: big GEMM via bf16 MFMA, h folded AFTER the MFMA (zero A-build VALU).
// out[s,o] = sum_j hh1[s,j] * P_j[s,o],  P_j = emb[s,:] (bf16, in VGPRs)
//            @ B_j (128x64 bf16, LDS-staged per j).
// Grid: 128 M-tiles x splitK=4 (j-quarters). 256 thr = 4 waves; wave w owns
// rows (w>>1)*32..+32, cols (w&1)*32..+32 (2x2 frags of 16x16).
// ---------------------------------------------------------------------------
__global__ __launch_bounds__(256) void k_bigmm_mfma(
    const unsigned short* __restrict__ embb, const float* __restrict__ hh1g,
    const unsigned short* __restrict__ W_swz, float* __restrict__ partials)
{
    __shared__ uint4 w_lds[1024];          // 16 KB: [ks][nt][lane] fragments
    __shared__ float hh1_lds[64][33];      // 8.45 KB
    int tid = threadIdx.x;
    int w = tid >> 6, lane = tid & 63;
    int mt = blockIdx.x >> 2, ksp = blockIdx.x & 3;
    int s0 = mt * 64, j0 = ksp * 32;

    // stage hh1 tile (rows s0..+64, j-range j0..+32)
#pragma unroll
    for (int it = 0; it < 8; ++it) {
        int idx = tid + it * 256;
        int r = idx >> 5, jj = idx & 31;
        hh1_lds[r][jj] = hh1g[(size_t)(s0 + r) * 128 + j0 + jj];
    }

    // pin this lane's emb bf16 A-fragments: 2 row-tiles x 4 k-steps x 8 bf16
    bf16x8 emb_r[2][4];
    int rbase = s0 + (w >> 1) * 32 + (lane & 15);
    int cbase = (lane >> 4) * 8;
#pragma unroll
    for (int rt = 0; rt < 2; ++rt)
#pragma unroll
        for (int ks = 0; ks < 4; ++ks)
            emb_r[rt][ks] = *(const bf16x8*)&embb[(size_t)(rbase + rt * 16) * 128 + ks * 32 + cbase];

    // prefetch first W_j fragment block (16 KB per j)
    const uint4* Wg = (const uint4*)W_swz;   // 1024 uint4 per j
    uint4 wreg[4];
#pragma unroll
    for (int q = 0; q < 4; ++q) wreg[q] = Wg[(size_t)j0 * 1024 + q * 256 + tid];

    int nt0 = (w & 1) * 2;
    f32x4 acc[2][2];
#pragma unroll
    for (int a = 0; a < 2; ++a)
#pragma unroll
        for (int b = 0; b < 2; ++b) acc[a][b] = (f32x4){0.f, 0.f, 0.f, 0.f};

    int rl0 = (w >> 1) * 32 + 4 * (lane >> 4);   // hh1_lds row base for r=0, rt=0
    for (int jj = 0; jj < 32; ++jj) {
        __syncthreads();
#pragma unroll
        for (int q = 0; q < 4; ++q) w_lds[q * 256 + tid] = wreg[q];
        if (jj < 31) {
#pragma unroll
            for (int q = 0; q < 4; ++q) wreg[q] = Wg[(size_t)(j0 + jj + 1) * 1024 + q * 256 + tid];
        }
        __syncthreads();
        // P_j = emb @ B_j   (pure MFMA chain, P init 0)
        f32x4 P00 = (f32x4){0.f, 0.f, 0.f, 0.f};
        f32x4 P01 = (f32x4){0.f, 0.f, 0.f, 0.f};
        f32x4 P10 = (f32x4){0.f, 0.f, 0.f, 0.f};
        f32x4 P11 = (f32x4){0.f, 0.f, 0.f, 0.f};
#pragma unroll
        for (int ks = 0; ks < 4; ++ks) {
            bf16x8 b0 = *(const bf16x8*)&w_lds[(ks * 4 + nt0) * 64 + lane];
            bf16x8 b1 = *(const bf16x8*)&w_lds[(ks * 4 + nt0 + 1) * 64 + lane];
            P00 = __builtin_amdgcn_mfma_f32_16x16x32_bf16(emb_r[0][ks], b0, P00, 0, 0, 0);
            P01 = __builtin_amdgcn_mfma_f32_16x16x32_bf16(emb_r[0][ks], b1, P01, 0, 0, 0);
            P10 = __builtin_amdgcn_mfma_f32_16x16x32_bf16(emb_r[1][ks], b0, P10, 0, 0, 0);
            P11 = __builtin_amdgcn_mfma_f32_16x16x32_bf16(emb_r[1][ks], b1, P11, 0, 0, 0);
        }
        // fold h: acc[rt][nt][r] += h[row(rt,r)] * P[rt][nt][r]
        // D layout row = 4*(lane>>4)+r  -> h row = rl0 + rt*16 + r (broadcast reads)
#pragma unroll
        for (int r = 0; r < 4; ++r) {
            float h0 = hh1_lds[rl0 + r][jj];
            float h1 = hh1_lds[rl0 + 16 + r][jj];
            acc[0][0][r] += h0 * P00[r];
            acc[0][1][r] += h0 * P01[r];
            acc[1][0][r] += h1 * P10[r];
            acc[1][1][r] += h1 * P11[r];
        }
    }
    // epilogue: D layout col=lane&15, row=4*(lane>>4)+r (m89-verified)
    float* pb = partials + (size_t)ksp * (NS * 64);
#pragma unroll
    for (int rt = 0; rt < 2; ++rt) {
#pragma unroll
        for (int n = 0; n < 2; ++n) {
            int colg = (w & 1) * 32 + n * 16 + (lane & 15);
#pragma unroll
            for (int r = 0; r < 4; ++r) {
                int rowg = s0 + (w >> 1) * 32 + rt * 16 + 4 * (lane >> 4) + r;
                pb[(size_t)rowg * 64 + colg] = acc[rt][n][r];
            }
        }
    }
}

// ---------------------------------------------------------------------------
// K5: epilogue. h1 = relu(sum_k partials + b1eff); logits = h1@w2 + b2.
// ---------------------------------------------------------------------------
__global__ __launch_bounds__(256) void k_final(
    const float* __restrict__ partials, const float* __restrict__ b1eff,
    const float* __restrict__ w2h, const float* __restrict__ b2h, float* __restrict__ out)
{
    int tid = threadIdx.x;
    int wv = tid >> 6, lane = tid & 63;
    int s = blockIdx.x * 4 + wv;
    float h1 = b1eff[(size_t)s * 64 + lane];
#pragma unroll
    for (int ks = 0; ks < 4; ++ks) h1 += partials[(size_t)ks * (NS * 64) + (size_t)s * 64 + lane];
    h1 = fmaxf(h1, 0.0f);
    float lg[5];
#pragma unroll
    for (int aa = 0; aa < 5; ++aa) lg[aa] = h1 * w2h[(size_t)s * 320 + lane * 5 + aa];
#pragma unroll
    for (int off = 32; off >= 1; off >>= 1) {
#pragma unroll
        for (int aa = 0; aa < 5; ++aa) lg[aa] += __shfl_xor(lg[aa], off, 64);
    }
    if (lane == 0) {
#pragma unroll
        for (int aa = 0; aa < 5; ++aa)
            out[16384 + (size_t)s * 5 + aa] = lg[aa] + b2h[(size_t)s * 5 + aa];
    }
}

// ---------------------------------------------------------------------------
extern "C" void kernel_launch(void* const* d_in, const int* in_sizes, int n_in,
                              void* d_out, int out_size, void* d_ws, size_t ws_size,
                              hipStream_t stream)
{
    (void)in_sizes; (void)n_in; (void)out_size; (void)ws_size;
    const float* hidden  = (const float*)d_in[0];
    const float* fobs    = (const float*)d_in[1];
    const int*   dones   = (const int*)d_in[2];
    const float* embed_w = (const float*)d_in[3];
    const float* embed_b = (const float*)d_in[4];
    const float* gru_wi  = (const float*)d_in[5];
    const float* gru_wh  = (const float*)d_in[6];
    const float* gru_bh  = (const float*)d_in[7];
    const float* tWq  = (const float*)d_in[8];
    const float* tWk  = (const float*)d_in[9];
    const float* tWv  = (const float*)d_in[10];
    const float* tWo  = (const float*)d_in[11];
    const float* ln1s = (const float*)d_in[12];
    const float* ln1b = (const float*)d_in[13];
    const float* ffw1 = (const float*)d_in[14];
    const float* ffb1 = (const float*)d_in[15];
    const float* ffw2 = (const float*)d_in[16];
    const float* ffb2 = (const float*)d_in[17];
    const float* ln2s = (const float*)d_in[18];
    const float* ln2b = (const float*)d_in[19];
    const float* hw1_1 = (const float*)d_in[20]; const float* hb1_1 = (const float*)d_in[21];
    const float* hw2_1 = (const float*)d_in[22]; const float* hb2_1 = (const float*)d_in[23];
    const float* hw1_2 = (const float*)d_in[24]; const float* hb1_2 = (const float*)d_in[25];
    const float* hw2_2 = (const float*)d_in[26]; const float* hb2_2 = (const float*)d_in[27];
    const float* hw1_3 = (const float*)d_in[28]; const float* hb1_3 = (const float*)d_in[29];
    const float* hw2_3 = (const float*)d_in[30]; const float* hb2_3 = (const float*)d_in[31];
    const float* hw1_4 = (const float*)d_in[32]; const float* hb1_4 = (const float*)d_in[33];
    const float* hw2_4 = (const float*)d_in[34]; const float* hb2_4 = (const float*)d_in[35];
    float* out = (float*)d_out;
    float* ws  = (float*)d_ws;

    // workspace layout (floats). Overlays:
    //  - parts (8 MB) aliases gi (12 MB, dead after k_gru)
    //  - W_swz (2 MB) + emb_bf16 (2 MB) alias emb (4 MB, dead after k_gi)
    float* gi      = ws;                      // 8192*384
    float* parts   = ws;                      // 4*8192*64 (aliases gi)
    float* emb     = gi      + 3145728;       // 8192*128 (dead after k_gi)
    unsigned short* W_swz    = (unsigned short*)emb;              // 1M bf16 = 2 MB
    unsigned short* emb_bf16 = (unsigned short*)(emb + 524288);   // 1M bf16 = 2 MB
    float* emb_seq = emb     + 1048576;       // 8192*128
    float* cap_rep = emb_seq + 1048576;       // 8192*8
    float* hh1g    = cap_rep + 65536;         // 8192*128
    float* b1eff_  = hh1g    + 1048576;       // 8192*64
    float* w2hb    = b1eff_  + 524288;        // 8192*320
    float* b2hb    = w2hb    + 2621440;       // 8192*5

    k_embed<<<128, 256, 0, stream>>>(fobs, embed_w, embed_b, emb);
    k_gi<<<768, 256, 0, stream>>>(emb, gru_wi, gi);
    k_prepW<<<512, 256, 0, stream>>>(hw2_1, W_swz);
    k_gru<<<128, 768, 0, stream>>>(gi, gru_wh, gru_bh, dones, hidden, emb_seq, emb_bf16, out);
    k_attn<<<256, 256, 0, stream>>>(fobs, tWq, tWk, tWv, tWo, ln1s, ln1b,
                                    ffw1, ffb1, ffw2, ffb2, ln2s, ln2b, cap_rep);
    k_hyper<<<512, 256, 0, stream>>>(cap_rep, emb_seq,
                                     hw1_1, hb1_1, hw1_2, hb1_2, hw1_3, hb1_3, hw1_4, hb1_4,
                                     hb2_1, hw2_2, hb2_2, hw2_3, hb2_3, hw2_4, hb2_4,
                                     hh1g, b1eff_, w2hb, b2hb);
    k_bigmm_mfma<<<512, 256, 0, stream>>>(emb_bf16, hh1g, W_swz, parts);
    k_final<<<2048, 256, 0, stream>>>(parts, b1eff_, w2hb, b2hb, out);
}

// Round 6
// 381.394 us; speedup vs baseline: 1.6064x; 1.0643x over previous
//
#include <hip/hip_runtime.h>
#include <hip/hip_bf16.h>
#include <stdint.h>

// Problem constants
#define TT 64
#define BB 128
#define OBSD 64
#define FOBS 120   // OBS_D + CAP_D
#define FC 128
#define G3 384
#define NS 8192    // T*B
#define DD 8
#define FF 64
#define HN 128
#define TGT 64
#define ADIM 5

typedef __attribute__((ext_vector_type(8))) short bf16x8;
typedef __attribute__((ext_vector_type(4))) float f32x4;

__device__ __forceinline__ float sigmoidf_(float x) { return 1.0f / (1.0f + __expf(-x)); }
__device__ __forceinline__ float tanhf_(float x) {
    float e = __expf(-2.0f * fabsf(x));
    float r = (1.0f - e) / (1.0f + e);
    return copysignf(r, x);
}
__device__ __forceinline__ unsigned short f2bf_rne(float x) {
    unsigned u = __float_as_uint(x);
    return (unsigned short)((u + 0x7fffu + ((u >> 16) & 1u)) >> 16);
}

// ---------------------------------------------------------------------------
// K1a: emb = relu(obs @ embed_w + embed_b)   (8192 x 64) @ (64 x 128)
// ---------------------------------------------------------------------------
__global__ __launch_bounds__(256) void k_embed(
    const float* __restrict__ fobs, const float* __restrict__ We,
    const float* __restrict__ be, float* __restrict__ emb)
{
    __shared__ float obs_t[64][68];
    __shared__ float W_t[64][128];
    int tid = threadIdx.x;
    int s0 = blockIdx.x * 64;
    {
        int rl = tid >> 4, e4 = tid & 15;
#pragma unroll
        for (int rr = 0; rr < 4; ++rr) {
            int r = rl + rr * 16;
            float4 v = *(const float4*)&fobs[(size_t)(s0 + r) * FOBS + e4 * 4];
            *(float4*)&obs_t[r][e4 * 4] = v;
        }
    }
#pragma unroll
    for (int i = 0; i < 8; ++i) {
        int idx = tid + i * 256;
        int e = idx >> 5, c4 = idx & 31;
        float4 v = *(const float4*)&We[(size_t)e * 128 + c4 * 4];
        *(float4*)&W_t[e][c4 * 4] = v;
    }
    __syncthreads();
    int c = tid & 127, half = tid >> 7;
    float acc[32];
    float bc = be[c];
#pragma unroll
    for (int k = 0; k < 32; ++k) acc[k] = bc;
#pragma unroll
    for (int e4 = 0; e4 < 16; ++e4) {
        float w0 = W_t[4 * e4 + 0][c], w1 = W_t[4 * e4 + 1][c];
        float w2 = W_t[4 * e4 + 2][c], w3 = W_t[4 * e4 + 3][c];
#pragma unroll
        for (int k = 0; k < 32; ++k) {
            float4 ov = *(const float4*)&obs_t[half * 32 + k][e4 * 4];
            acc[k] += ov.x * w0 + ov.y * w1 + ov.z * w2 + ov.w * w3;
        }
    }
#pragma unroll
    for (int k = 0; k < 32; ++k)
        emb[(size_t)(s0 + half * 32 + k) * FC + c] = fmaxf(acc[k], 0.0f);
}

// ---------------------------------------------------------------------------
// K1b: gi = emb @ gru_wi    (8192 x 128) @ (128 x 384)
// ---------------------------------------------------------------------------
__global__ __launch_bounds__(256) void k_gi(
    const float* __restrict__ emb, const float* __restrict__ Wi, float* __restrict__ gi)
{
    __shared__ float e_t[64][132];
    __shared__ float w_t[128 * 64];
    int tid = threadIdx.x;
    int st = blockIdx.x / 6, gt = blockIdx.x % 6;
    int s0 = st * 64, g0 = gt * 64;
#pragma unroll
    for (int i = 0; i < 8; ++i) {
        int idx = tid + i * 256;
        int r = idx >> 5, c4 = idx & 31;
        float4 v = *(const float4*)&emb[(size_t)(s0 + r) * FC + c4 * 4];
        *(float4*)&e_t[r][c4 * 4] = v;
    }
#pragma unroll
    for (int i = 0; i < 8; ++i) {
        int idx = tid + i * 256;
        int r = idx >> 4, g4 = idx & 15;
        float4 v = *(const float4*)&Wi[(size_t)r * G3 + g0 + g4 * 4];
        *(float4*)&w_t[r * 64 + g4 * 4] = v;
    }
    __syncthreads();
    int sb4 = (tid >> 4) * 4, ob4 = (tid & 15) * 4;
    float acc[4][4];
#pragma unroll
    for (int a = 0; a < 4; ++a)
#pragma unroll
        for (int b = 0; b < 4; ++b) acc[a][b] = 0.0f;
    for (int c4 = 0; c4 < 32; ++c4) {
        float4 e4[4], w4[4];
#pragma unroll
        for (int si = 0; si < 4; ++si) e4[si] = *(const float4*)&e_t[sb4 + si][c4 * 4];
#pragma unroll
        for (int cc = 0; cc < 4; ++cc) w4[cc] = *(const float4*)&w_t[(c4 * 4 + cc) * 64 + ob4];
#pragma unroll
        for (int si = 0; si < 4; ++si) {
            const float* ep = (const float*)&e4[si];
#pragma unroll
            for (int cc = 0; cc < 4; ++cc) {
                float ev = ep[cc];
                const float* wp = (const float*)&w4[cc];
                acc[si][0] += ev * wp[0];
                acc[si][1] += ev * wp[1];
                acc[si][2] += ev * wp[2];
                acc[si][3] += ev * wp[3];
            }
        }
    }
#pragma unroll
    for (int si = 0; si < 4; ++si) {
        float4 sv;
        sv.x = acc[si][0]; sv.y = acc[si][1]; sv.z = acc[si][2]; sv.w = acc[si][3];
        *(float4*)&gi[(size_t)(s0 + sb4 + si) * G3 + g0 + ob4] = sv;
    }
}

// ---------------------------------------------------------------------------
// K1c: pre-swizzle hw2_1 into bf16 MFMA B-fragment order.
// B[k][o], k=j*128+c (16384 x 64).  Fragment (j,ks,nt): 64 lanes x 8 bf16,
// element (lane,i) = B[j*128 + ks*32 + (lane>>4)*8 + i][nt*16 + (lane&15)].
// ---------------------------------------------------------------------------
__global__ __launch_bounds__(256) void k_prepW(
    const float* __restrict__ W, unsigned short* __restrict__ W_swz)
{
    int fid = blockIdx.x * 256 + threadIdx.x;       // 0..131071 fragment-lane id
    int lane = fid & 63;
    int nt = (fid >> 6) & 3;
    int ks = (fid >> 8) & 3;
    int j  = fid >> 10;
    int col = nt * 16 + (lane & 15);
    int kbase = ks * 32 + ((lane >> 4) * 8);
    const float* src = W + ((size_t)j * 128 + kbase) * 64 + col;
    unsigned short o[8];
#pragma unroll
    for (int i = 0; i < 8; ++i) o[i] = f2bf_rne(src[(size_t)i * 64]);
    *(uint4*)&W_swz[(size_t)fid * 8] = *(const uint4*)o;
}

// ---------------------------------------------------------------------------
// K2: GRU scan, v2. One WG per batch element, 512 threads = 4 threads/column.
// Each thread pins a 96-element Wh slice (3 gates x 32-row quarter) in VGPRs;
// quad shfl_xor reduce; gi/dones prefetched 2 steps ahead into registers;
// h double-buffered in LDS (padded quarters) -> ONE barrier per step.
// ---------------------------------------------------------------------------
__global__ __launch_bounds__(512, 2) void k_gru(
    const float* __restrict__ gi, const float* __restrict__ Wh, const float* __restrict__ bh,
    const int* __restrict__ dones, const float* __restrict__ h0,
    float* __restrict__ emb_seq, unsigned short* __restrict__ embb,
    float* __restrict__ hid_out)
{
    __shared__ float h_lds[2][144];     // 4 quarters x 36 floats (padded), x2 buffers
    int b = blockIdx.x, tid = threadIdx.x;
    int c = tid >> 2, q = tid & 3;
    int posc = (c >> 5) * 36 + (c & 31);

    // pin Wh slice: W[g*32+i] = Wh[q*32+i][g*128+c]
    float W[96];
#pragma unroll
    for (int g = 0; g < 3; ++g)
#pragma unroll
        for (int i = 0; i < 32; ++i)
            W[g * 32 + i] = Wh[(size_t)(q * 32 + i) * G3 + g * 128 + c];
    float bq0 = bh[c], bq1 = bh[128 + c], bq2 = bh[256 + c];

    if (tid < 128) h_lds[0][(tid >> 5) * 36 + (tid & 31)] = h0[(size_t)b * FC + tid];

    // prefetch gi/dones for t=0 and t=1
    const float* g0p = gi + ((size_t)0 * BB + b) * G3;
    const float* g1p = gi + ((size_t)1 * BB + b) * G3;
    float gc0 = g0p[c], gc1 = g0p[128 + c], gc2 = g0p[256 + c];
    float n10 = g1p[c], n11 = g1p[128 + c], n12 = g1p[256 + c];
    int dval = dones[b];
    int dn1 = dones[BB + b];
    __syncthreads();

    int cur = 0;
    for (int t = 0; t < TT; ++t) {
        // issue prefetch for t+2 (in flight during the matvec below)
        int t2 = (t + 2 < TT) ? t + 2 : TT - 1;
        const float* gp2 = gi + ((size_t)t2 * BB + b) * G3;
        float p0 = gp2[c], p1 = gp2[128 + c], p2 = gp2[256 + c];
        int pd = dones[t2 * BB + b];

        // matvec quarter: d[g] = sum_i W[g][i] * h[q*32+i]
        float d0 = 0.f, d1 = 0.f, d2 = 0.f;
        const float* hb = &h_lds[cur][q * 36];
#pragma unroll
        for (int i4 = 0; i4 < 8; ++i4) {
            float4 h4 = *(const float4*)&hb[i4 * 4];
            const float* hp = (const float*)&h4;
#pragma unroll
            for (int e = 0; e < 4; ++e) {
                int i = i4 * 4 + e;
                d0 += W[i] * hp[e];
                d1 += W[32 + i] * hp[e];
                d2 += W[64 + i] * hp[e];
            }
        }
        // quad reduce (lanes {4k..4k+3})
        d0 += __shfl_xor(d0, 1, 64); d0 += __shfl_xor(d0, 2, 64);
        d1 += __shfl_xor(d1, 1, 64); d1 += __shfl_xor(d1, 2, 64);
        d2 += __shfl_xor(d2, 1, 64); d2 += __shfl_xor(d2, 2, 64);

        float hs = dval ? 0.0f : 1.0f;
        float hold = h_lds[cur][posc];
        float r = sigmoidf_(gc0 + d0 * hs + bq0);
        float z = sigmoidf_(gc1 + d1 * hs + bq1);
        float n = tanhf_(gc2 + r * (d2 * hs + bq2));
        float hnew = (1.0f - z) * n + z * (hs * hold);

        if (q == 0) {
            h_lds[cur ^ 1][posc] = hnew;
            emb_seq[((size_t)t * BB + b) * FC + c] = hnew;
            embb[((size_t)t * BB + b) * FC + c] = f2bf_rne(hnew);
        }
        // rotate prefetch registers
        gc0 = n10; gc1 = n11; gc2 = n12;
        n10 = p0;  n11 = p1;  n12 = p2;
        dval = dn1; dn1 = pd;
        __syncthreads();
        cur ^= 1;
    }
    if (tid < 128) hid_out[(size_t)b * FC + tid] = h_lds[cur][(tid >> 5) * 36 + (tid & 31)];
}

// ---------------------------------------------------------------------------
// K3: tiny transformer on capability features.
// ---------------------------------------------------------------------------
__global__ __launch_bounds__(256) void k_attn(
    const float* __restrict__ fobs,
    const float* __restrict__ tWq, const float* __restrict__ tWk,
    const float* __restrict__ tWv, const float* __restrict__ tWo,
    const float* __restrict__ ln1s, const float* __restrict__ ln1b,
    const float* __restrict__ ffw1, const float* __restrict__ ffb1,
    const float* __restrict__ ffw2, const float* __restrict__ ffb2,
    const float* __restrict__ ln2s, const float* __restrict__ ln2b,
    float* __restrict__ cap_repr)
{
    __shared__ float wq[2][8][8], wk[2][8][8], wv[2][8][8], wo[2][8][8];
    __shared__ float l1s[2][8], l1b[2][8], l2s[2][8], l2b[2][8];
    __shared__ float f1[2][8][64], fb1[2][64];
    __shared__ float f2[2][64][8], fb2w[2][8];
    __shared__ float k_l[32][8][9], v_l[32][8][9];
    int tid = threadIdx.x;
    for (int i = tid; i < 128; i += 256) {
        ((float*)wq)[i] = tWq[i]; ((float*)wk)[i] = tWk[i];
        ((float*)wv)[i] = tWv[i]; ((float*)wo)[i] = tWo[i];
        ((float*)fb1)[i] = ffb1[i];
    }
    if (tid < 16) {
        ((float*)l1s)[tid] = ln1s[tid]; ((float*)l1b)[tid] = ln1b[tid];
        ((float*)l2s)[tid] = ln2s[tid]; ((float*)l2b)[tid] = ln2b[tid];
        ((float*)fb2w)[tid] = ffb2[tid];
    }
    for (int i = tid; i < 1024; i += 256) { ((float*)f1)[i] = ffw1[i]; ((float*)f2)[i] = ffw2[i]; }
    int sl = tid >> 3, a = tid & 7;
    int s = blockIdx.x * 32 + sl;
    float x[8];
#pragma unroll
    for (int i = 0; i < 7; ++i) x[i] = fobs[(size_t)s * FOBS + OBSD + a * 7 + i];
    x[7] = (a == 0) ? 1.0f : 0.0f;
    __syncthreads();
    for (int l = 0; l < 2; ++l) {
        float q[8], k[8], v[8];
#pragma unroll
        for (int d = 0; d < 8; ++d) { q[d] = 0.f; k[d] = 0.f; v[d] = 0.f; }
#pragma unroll
        for (int e = 0; e < 8; ++e) {
            float xe = x[e];
#pragma unroll
            for (int d = 0; d < 8; ++d) {
                q[d] += xe * wq[l][e][d];
                k[d] += xe * wk[l][e][d];
                v[d] += xe * wv[l][e][d];
            }
        }
#pragma unroll
        for (int d = 0; d < 8; ++d) { k_l[sl][a][d] = k[d]; v_l[sl][a][d] = v[d]; }
        __syncthreads();
        float o[8];
#pragma unroll
        for (int h = 0; h < 4; ++h) {
            float sc[8]; float mx = -1e30f;
#pragma unroll
            for (int ka = 0; ka < 8; ++ka) {
                float sv = (q[2 * h] * k_l[sl][ka][2 * h] + q[2 * h + 1] * k_l[sl][ka][2 * h + 1])
                           * 0.70710678118654752f;
                sc[ka] = sv; mx = fmaxf(mx, sv);
            }
            float ssum = 0.f;
#pragma unroll
            for (int ka = 0; ka < 8; ++ka) { sc[ka] = __expf(sc[ka] - mx); ssum += sc[ka]; }
            float inv = 1.0f / ssum;
            float o0 = 0.f, o1 = 0.f;
#pragma unroll
            for (int ka = 0; ka < 8; ++ka) {
                float at = sc[ka] * inv;
                o0 += at * v_l[sl][ka][2 * h];
                o1 += at * v_l[sl][ka][2 * h + 1];
            }
            o[2 * h] = o0; o[2 * h + 1] = o1;
        }
        float y[8];
#pragma unroll
        for (int e = 0; e < 8; ++e) y[e] = x[e];
#pragma unroll
        for (int d = 0; d < 8; ++d) {
            float od = o[d];
#pragma unroll
            for (int e = 0; e < 8; ++e) y[e] += od * wo[l][d][e];
        }
        {
            float m = 0.f;
#pragma unroll
            for (int e = 0; e < 8; ++e) m += y[e];
            m *= 0.125f;
            float vv = 0.f;
#pragma unroll
            for (int e = 0; e < 8; ++e) { float dd = y[e] - m; vv += dd * dd; }
            vv *= 0.125f;
            float rs = rsqrtf(vv + 1e-6f);
#pragma unroll
            for (int e = 0; e < 8; ++e)
                x[e] = 2.0f * ((y[e] - m) * rs * l1s[l][e] + l1b[l][e]);
        }
        float t1[64];
#pragma unroll
        for (int f = 0; f < 64; ++f) t1[f] = 0.f;
#pragma unroll
        for (int e = 0; e < 8; ++e) {
            float xe = x[e];
#pragma unroll
            for (int f = 0; f < 64; ++f) t1[f] += xe * f1[l][e][f];
        }
        float y2[8];
#pragma unroll
        for (int e = 0; e < 8; ++e) y2[e] = x[e] + fb2w[l][e];   // residual + ffb2
#pragma unroll
        for (int f = 0; f < 64; ++f) {
            float tf = fmaxf(t1[f] + fb1[l][f], 0.0f);
#pragma unroll
            for (int e = 0; e < 8; ++e) y2[e] += tf * f2[l][f][e];
        }
        {
            float m = 0.f;
#pragma unroll
            for (int e = 0; e < 8; ++e) m += y2[e];
            m *= 0.125f;
            float vv = 0.f;
#pragma unroll
            for (int e = 0; e < 8; ++e) { float dd = y2[e] - m; vv += dd * dd; }
            vv *= 0.125f;
            float rs = rsqrtf(vv + 1e-6f);
#pragma unroll
            for (int e = 0; e < 8; ++e)
                x[e] = 2.0f * ((y2[e] - m) * rs * l2s[l][e] + l2b[l][e]);
        }
        __syncthreads();
    }
#pragma unroll
    for (int e = 0; e < 8; ++e) {
        float xv = x[e];
        xv += __shfl_xor(xv, 1, 8);
        xv += __shfl_xor(xv, 2, 8);
        xv += __shfl_xor(xv, 4, 8);
        if (a == 0) cap_repr[(size_t)s * 8 + e] = xv * 0.125f;
    }
}

// ---------------------------------------------------------------------------
// K3b: hypernet first layers + small second layers.
// ---------------------------------------------------------------------------
__global__ __launch_bounds__(256) void k_hyper(
    const float* __restrict__ cap_repr, const float* __restrict__ emb_seq,
    const float* __restrict__ hw1_1, const float* __restrict__ hb1_1,
    const float* __restrict__ hw1_2, const float* __restrict__ hb1_2,
    const float* __restrict__ hw1_3, const float* __restrict__ hb1_3,
    const float* __restrict__ hw1_4, const float* __restrict__ hb1_4,
    const float* __restrict__ hb2_1,
    const float* __restrict__ hw2_2, const float* __restrict__ hb2_2,
    const float* __restrict__ hw2_3, const float* __restrict__ hb2_3,
    const float* __restrict__ hw2_4, const float* __restrict__ hb2_4,
    float* __restrict__ hh1g, float* __restrict__ b1eff,
    float* __restrict__ w2h, float* __restrict__ b2h)
{
    __shared__ float cr[16][8];
    __shared__ float hh[4][16][132];
    __shared__ float es[16][132];
    int tid = threadIdx.x;
    int s0 = blockIdx.x * 16;
    if (tid < 128) ((float*)cr)[tid] = cap_repr[(size_t)s0 * 8 + tid];
#pragma unroll
    for (int i = 0; i < 2; ++i) {
        int idx = tid + i * 256;
        int r = idx >> 5, c4 = idx & 31;
        float4 v = *(const float4*)&emb_seq[(size_t)(s0 + r) * FC + c4 * 4];
        *(float4*)&es[r][c4 * 4] = v;
    }
    __syncthreads();
#pragma unroll
    for (int it = 0; it < 32; ++it) {
        int idx = tid + it * 256;
        int u = idx & 127;
        int sn = (idx >> 7) & 15;
        int n = idx >> 11;
        const float* w = (n == 0) ? hw1_1 : ((n == 1) ? hw1_2 : ((n == 2) ? hw1_3 : hw1_4));
        const float* bb = (n == 0) ? hb1_1 : ((n == 1) ? hb1_2 : ((n == 2) ? hb1_3 : hb1_4));
        float acc = bb[u];
#pragma unroll
        for (int e = 0; e < 8; ++e) acc += cr[sn][e] * w[e * 128 + u];
        acc = fmaxf(acc, 0.0f);
        hh[n][sn][u] = acc;
        if (n == 0) hh1g[(size_t)(s0 + sn) * 128 + u] = acc;
    }
    __syncthreads();
#pragma unroll
    for (int it = 0; it < 4; ++it) {
        int idx = tid + it * 256;
        int o = idx & 63, sn = idx >> 6;
        float acc = hb2_2[o];
        for (int j = 0; j < 128; ++j) acc += hh[1][sn][j] * hw2_2[j * 64 + o];
        for (int c = 0; c < 128; ++c) acc += es[sn][c] * hb2_1[c * 64 + o];
        b1eff[(size_t)(s0 + sn) * 64 + o] = acc;
    }
    for (int it = 0; it < 2; ++it) {
        int oa = tid + it * 256;
        if (oa < 320) {
            float acc[16];
#pragma unroll
            for (int sn = 0; sn < 16; ++sn) acc[sn] = 0.f;
            for (int j = 0; j < 128; ++j) {
                float w = hw2_3[j * 320 + oa];
#pragma unroll
                for (int sn = 0; sn < 16; ++sn) acc[sn] += hh[2][sn][j] * w;
            }
            float bb = hb2_3[oa];
#pragma unroll
            for (int sn = 0; sn < 16; ++sn) w2h[(size_t)(s0 + sn) * 320 + oa] = acc[sn] + bb;
        }
    }
    if (tid < 80) {
        int aa = tid % 5, sn = tid / 5;
        float acc = hb2_4[aa];
        for (int j = 0; j < 128; ++j) acc += hh[3][sn][j] * hw2_4[j * 5 + aa];
        b2h[(size_t)(s0 + sn) * 5 + aa] = acc;
    }
}

// ---------------------------------------------------------------------------
// K4: big GEMM via bf16 MFMA, h folded AFTER the MFMA (zero A-build VALU).
// ---------------------------------------------------------------------------
__global__ __launch_bounds__(256) void k_bigmm_mfma(
    const unsigned short* __restrict__ embb, const float* __restrict__ hh1g,
    const unsigned short* __restrict__ W_swz, float* __restrict__ partials)
{
    __shared__ uint4 w_lds[1024];          // 16 KB: [ks][nt][lane] fragments
    __shared__ float hh1_lds[64][33];      // 8.45 KB
    int tid = threadIdx.x;
    int w = tid >> 6, lane = tid & 63;
    int mt = blockIdx.x >> 2, ksp = blockIdx.x & 3;
    int s0 = mt * 64, j0 = ksp * 32;

    // stage hh1 tile (rows s0..+64, j-range j0..+32)
#pragma unroll
    for (int it = 0; it < 8; ++it) {
        int idx = tid + it * 256;
        int r = idx >> 5, jj = idx & 31;
        hh1_lds[r][jj] = hh1g[(size_t)(s0 + r) * 128 + j0 + jj];
    }

    // pin this lane's emb bf16 A-fragments: 2 row-tiles x 4 k-steps x 8 bf16
    bf16x8 emb_r[2][4];
    int rbase = s0 + (w >> 1) * 32 + (lane & 15);
    int cbase = (lane >> 4) * 8;
#pragma unroll
    for (int rt = 0; rt < 2; ++rt)
#pragma unroll
        for (int ks = 0; ks < 4; ++ks)
            emb_r[rt][ks] = *(const bf16x8*)&embb[(size_t)(rbase + rt * 16) * 128 + ks * 32 + cbase];

    // prefetch first W_j fragment block (16 KB per j)
    const uint4* Wg = (const uint4*)W_swz;   // 1024 uint4 per j
    uint4 wreg[4];
#pragma unroll
    for (int q = 0; q < 4; ++q) wreg[q] = Wg[(size_t)j0 * 1024 + q * 256 + tid];

    int nt0 = (w & 1) * 2;
    f32x4 acc[2][2];
#pragma unroll
    for (int a = 0; a < 2; ++a)
#pragma unroll
        for (int b = 0; b < 2; ++b) acc[a][b] = (f32x4){0.f, 0.f, 0.f, 0.f};

    int rl0 = (w >> 1) * 32 + 4 * (lane >> 4);   // hh1_lds row base for r=0, rt=0
    for (int jj = 0; jj < 32; ++jj) {
        __syncthreads();
#pragma unroll
        for (int q = 0; q < 4; ++q) w_lds[q * 256 + tid] = wreg[q];
        if (jj < 31) {
#pragma unroll
            for (int q = 0; q < 4; ++q) wreg[q] = Wg[(size_t)(j0 + jj + 1) * 1024 + q * 256 + tid];
        }
        __syncthreads();
        // P_j = emb @ B_j   (pure MFMA chain, P init 0)
        f32x4 P00 = (f32x4){0.f, 0.f, 0.f, 0.f};
        f32x4 P01 = (f32x4){0.f, 0.f, 0.f, 0.f};
        f32x4 P10 = (f32x4){0.f, 0.f, 0.f, 0.f};
        f32x4 P11 = (f32x4){0.f, 0.f, 0.f, 0.f};
#pragma unroll
        for (int ks = 0; ks < 4; ++ks) {
            bf16x8 b0 = *(const bf16x8*)&w_lds[(ks * 4 + nt0) * 64 + lane];
            bf16x8 b1 = *(const bf16x8*)&w_lds[(ks * 4 + nt0 + 1) * 64 + lane];
            P00 = __builtin_amdgcn_mfma_f32_16x16x32_bf16(emb_r[0][ks], b0, P00, 0, 0, 0);
            P01 = __builtin_amdgcn_mfma_f32_16x16x32_bf16(emb_r[0][ks], b1, P01, 0, 0, 0);
            P10 = __builtin_amdgcn_mfma_f32_16x16x32_bf16(emb_r[1][ks], b0, P10, 0, 0, 0);
            P11 = __builtin_amdgcn_mfma_f32_16x16x32_bf16(emb_r[1][ks], b1, P11, 0, 0, 0);
        }
        // fold h: acc[rt][nt][r] += h[row(rt,r)] * P[rt][nt][r]
#pragma unroll
        for (int r = 0; r < 4; ++r) {
            float h0 = hh1_lds[rl0 + r][jj];
            float h1 = hh1_lds[rl0 + 16 + r][jj];
            acc[0][0][r] += h0 * P00[r];
            acc[0][1][r] += h0 * P01[r];
            acc[1][0][r] += h1 * P10[r];
            acc[1][1][r] += h1 * P11[r];
        }
    }
    // epilogue: D layout col=lane&15, row=4*(lane>>4)+r (m89-verified)
    float* pb = partials + (size_t)ksp * (NS * 64);
#pragma unroll
    for (int rt = 0; rt < 2; ++rt) {
#pragma unroll
        for (int n = 0; n < 2; ++n) {
            int colg = (w & 1) * 32 + n * 16 + (lane & 15);
#pragma unroll
            for (int r = 0; r < 4; ++r) {
                int rowg = s0 + (w >> 1) * 32 + rt * 16 + 4 * (lane >> 4) + r;
                pb[(size_t)rowg * 64 + colg] = acc[rt][n][r];
            }
        }
    }
}

// ---------------------------------------------------------------------------
// K5: epilogue. h1 = relu(sum_k partials + b1eff); logits = h1@w2 + b2.
// ---------------------------------------------------------------------------
__global__ __launch_bounds__(256) void k_final(
    const float* __restrict__ partials, const float* __restrict__ b1eff,
    const float* __restrict__ w2h, const float* __restrict__ b2h, float* __restrict__ out)
{
    int tid = threadIdx.x;
    int wv = tid >> 6, lane = tid & 63;
    int s = blockIdx.x * 4 + wv;
    float h1 = b1eff[(size_t)s * 64 + lane];
#pragma unroll
    for (int ks = 0; ks < 4; ++ks) h1 += partials[(size_t)ks * (NS * 64) + (size_t)s * 64 + lane];
    h1 = fmaxf(h1, 0.0f);
    float lg[5];
#pragma unroll
    for (int aa = 0; aa < 5; ++aa) lg[aa] = h1 * w2h[(size_t)s * 320 + lane * 5 + aa];
#pragma unroll
    for (int off = 32; off >= 1; off >>= 1) {
#pragma unroll
        for (int aa = 0; aa < 5; ++aa) lg[aa] += __shfl_xor(lg[aa], off, 64);
    }
    if (lane == 0) {
#pragma unroll
        for (int aa = 0; aa < 5; ++aa)
            out[16384 + (size_t)s * 5 + aa] = lg[aa] + b2h[(size_t)s * 5 + aa];
    }
}

// ---------------------------------------------------------------------------
extern "C" void kernel_launch(void* const* d_in, const int* in_sizes, int n_in,
                              void* d_out, int out_size, void* d_ws, size_t ws_size,
                              hipStream_t stream)
{
    (void)in_sizes; (void)n_in; (void)out_size; (void)ws_size;
    const float* hidden  = (const float*)d_in[0];
    const float* fobs    = (const float*)d_in[1];
    const int*   dones   = (const int*)d_in[2];
    const float* embed_w = (const float*)d_in[3];
    const float* embed_b = (const float*)d_in[4];
    const float* gru_wi  = (const float*)d_in[5];
    const float* gru_wh  = (const float*)d_in[6];
    const float* gru_bh  = (const float*)d_in[7];
    const float* tWq  = (const float*)d_in[8];
    const float* tWk  = (const float*)d_in[9];
    const float* tWv  = (const float*)d_in[10];
    const float* tWo  = (const float*)d_in[11];
    const float* ln1s = (const float*)d_in[12];
    const float* ln1b = (const float*)d_in[13];
    const float* ffw1 = (const float*)d_in[14];
    const float* ffb1 = (const float*)d_in[15];
    const float* ffw2 = (const float*)d_in[16];
    const float* ffb2 = (const float*)d_in[17];
    const float* ln2s = (const float*)d_in[18];
    const float* ln2b = (const float*)d_in[19];
    const float* hw1_1 = (const float*)d_in[20]; const float* hb1_1 = (const float*)d_in[21];
    const float* hw2_1 = (const float*)d_in[22]; const float* hb2_1 = (const float*)d_in[23];
    const float* hw1_2 = (const float*)d_in[24]; const float* hb1_2 = (const float*)d_in[25];
    const float* hw2_2 = (const float*)d_in[26]; const float* hb2_2 = (const float*)d_in[27];
    const float* hw1_3 = (const float*)d_in[28]; const float* hb1_3 = (const float*)d_in[29];
    const float* hw2_3 = (const float*)d_in[30]; const float* hb2_3 = (const float*)d_in[31];
    const float* hw1_4 = (const float*)d_in[32]; const float* hb1_4 = (const float*)d_in[33];
    const float* hw2_4 = (const float*)d_in[34]; const float* hb2_4 = (const float*)d_in[35];
    float* out = (float*)d_out;
    float* ws  = (float*)d_ws;

    // workspace layout (floats). Overlays:
    //  - parts (8 MB) aliases gi (12 MB, dead after k_gru)
    //  - W_swz (2 MB) + emb_bf16 (2 MB) alias emb (4 MB, dead after k_gi)
    float* gi      = ws;                      // 8192*384
    float* parts   = ws;                      // 4*8192*64 (aliases gi)
    float* emb     = gi      + 3145728;       // 8192*128 (dead after k_gi)
    unsigned short* W_swz    = (unsigned short*)emb;              // 1M bf16 = 2 MB
    unsigned short* emb_bf16 = (unsigned short*)(emb + 524288);   // 1M bf16 = 2 MB
    float* emb_seq = emb     + 1048576;       // 8192*128
    float* cap_rep = emb_seq + 1048576;       // 8192*8
    float* hh1g    = cap_rep + 65536;         // 8192*128
    float* b1eff_  = hh1g    + 1048576;       // 8192*64
    float* w2hb    = b1eff_  + 524288;        // 8192*320
    float* b2hb    = w2hb    + 2621440;       // 8192*5

    k_embed<<<128, 256, 0, stream>>>(fobs, embed_w, embed_b, emb);
    k_gi<<<768, 256, 0, stream>>>(emb, gru_wi, gi);
    k_prepW<<<512, 256, 0, stream>>>(hw2_1, W_swz);
    k_gru<<<128, 512, 0, stream>>>(gi, gru_wh, gru_bh, dones, hidden, emb_seq, emb_bf16, out);
    k_attn<<<256, 256, 0, stream>>>(fobs, tWq, tWk, tWv, tWo, ln1s, ln1b,
                                    ffw1, ffb1, ffw2, ffb2, ln2s, ln2b, cap_rep);
    k_hyper<<<512, 256, 0, stream>>>(cap_rep, emb_seq,
                                     hw1_1, hb1_1, hw1_2, hb1_2, hw1_3, hb1_3, hw1_4, hb1_4,
                                     hb2_1, hw2_2, hb2_2, hw2_3, hb2_3, hw2_4, hb2_4,
                                     hh1g, b1eff_, w2hb, b2hb);
    k_bigmm_mfma<<<512, 256, 0, stream>>>(emb_bf16, hh1g, W_swz, parts);
    k_final<<<2048, 256, 0, stream>>>(parts, b1eff_, w2hb, b2hb, out);
}

// Round 9
// 375.299 us; speedup vs baseline: 1.6325x; 1.0162x over previous
//
#include <hip/hip_runtime.h>
#include <hip/hip_bf16.h>
#include <stdint.h>

// Problem constants
#define TT 64
#define BB 128
#define OBSD 64
#define FOBS 120   // OBS_D + CAP_D
#define FC 128
#define G3 384
#define NS 8192    // T*B
#define DD 8
#define FF 64
#define HN 128
#define TGT 64
#define ADIM 5

typedef __attribute__((ext_vector_type(8))) short bf16x8;
typedef __attribute__((ext_vector_type(4))) float f32x4;

__device__ __forceinline__ float sigmoidf_(float x) { return 1.0f / (1.0f + __expf(-x)); }
__device__ __forceinline__ float tanhf_(float x) {
    float e = __expf(-2.0f * fabsf(x));
    float r = (1.0f - e) / (1.0f + e);
    return copysignf(r, x);
}
__device__ __forceinline__ unsigned short f2bf_rne(float x) {
    unsigned u = __float_as_uint(x);
    return (unsigned short)((u + 0x7fffu + ((u >> 16) & 1u)) >> 16);
}

// ---------------------------------------------------------------------------
// K1a: emb = relu(obs @ embed_w + embed_b)   (8192 x 64) @ (64 x 128)
// ---------------------------------------------------------------------------
__global__ __launch_bounds__(256) void k_embed(
    const float* __restrict__ fobs, const float* __restrict__ We,
    const float* __restrict__ be, float* __restrict__ emb)
{
    __shared__ float obs_t[64][68];
    __shared__ float W_t[64][128];
    int tid = threadIdx.x;
    int s0 = blockIdx.x * 64;
    {
        int rl = tid >> 4, e4 = tid & 15;
#pragma unroll
        for (int rr = 0; rr < 4; ++rr) {
            int r = rl + rr * 16;
            float4 v = *(const float4*)&fobs[(size_t)(s0 + r) * FOBS + e4 * 4];
            *(float4*)&obs_t[r][e4 * 4] = v;
        }
    }
#pragma unroll
    for (int i = 0; i < 8; ++i) {
        int idx = tid + i * 256;
        int e = idx >> 5, c4 = idx & 31;
        float4 v = *(const float4*)&We[(size_t)e * 128 + c4 * 4];
        *(float4*)&W_t[e][c4 * 4] = v;
    }
    __syncthreads();
    int c = tid & 127, half = tid >> 7;
    float acc[32];
    float bc = be[c];
#pragma unroll
    for (int k = 0; k < 32; ++k) acc[k] = bc;
#pragma unroll
    for (int e4 = 0; e4 < 16; ++e4) {
        float w0 = W_t[4 * e4 + 0][c], w1 = W_t[4 * e4 + 1][c];
        float w2 = W_t[4 * e4 + 2][c], w3 = W_t[4 * e4 + 3][c];
#pragma unroll
        for (int k = 0; k < 32; ++k) {
            float4 ov = *(const float4*)&obs_t[half * 32 + k][e4 * 4];
            acc[k] += ov.x * w0 + ov.y * w1 + ov.z * w2 + ov.w * w3;
        }
    }
#pragma unroll
    for (int k = 0; k < 32; ++k)
        emb[(size_t)(s0 + half * 32 + k) * FC + c] = fmaxf(acc[k], 0.0f);
}

// ---------------------------------------------------------------------------
// K1b: gi = emb @ gru_wi    (8192 x 128) @ (128 x 384)
// ---------------------------------------------------------------------------
__global__ __launch_bounds__(256) void k_gi(
    const float* __restrict__ emb, const float* __restrict__ Wi, float* __restrict__ gi)
{
    __shared__ float e_t[64][132];
    __shared__ float w_t[128 * 64];
    int tid = threadIdx.x;
    int st = blockIdx.x / 6, gt = blockIdx.x % 6;
    int s0 = st * 64, g0 = gt * 64;
#pragma unroll
    for (int i = 0; i < 8; ++i) {
        int idx = tid + i * 256;
        int r = idx >> 5, c4 = idx & 31;
        float4 v = *(const float4*)&emb[(size_t)(s0 + r) * FC + c4 * 4];
        *(float4*)&e_t[r][c4 * 4] = v;
    }
#pragma unroll
    for (int i = 0; i < 8; ++i) {
        int idx = tid + i * 256;
        int r = idx >> 4, g4 = idx & 15;
        float4 v = *(const float4*)&Wi[(size_t)r * G3 + g0 + g4 * 4];
        *(float4*)&w_t[r * 64 + g4 * 4] = v;
    }
    __syncthreads();
    int sb4 = (tid >> 4) * 4, ob4 = (tid & 15) * 4;
    float acc[4][4];
#pragma unroll
    for (int a = 0; a < 4; ++a)
#pragma unroll
        for (int b = 0; b < 4; ++b) acc[a][b] = 0.0f;
    for (int c4 = 0; c4 < 32; ++c4) {
        float4 e4[4], w4[4];
#pragma unroll
        for (int si = 0; si < 4; ++si) e4[si] = *(const float4*)&e_t[sb4 + si][c4 * 4];
#pragma unroll
        for (int cc = 0; cc < 4; ++cc) w4[cc] = *(const float4*)&w_t[(c4 * 4 + cc) * 64 + ob4];
#pragma unroll
        for (int si = 0; si < 4; ++si) {
            const float* ep = (const float*)&e4[si];
#pragma unroll
            for (int cc = 0; cc < 4; ++cc) {
                float ev = ep[cc];
                const float* wp = (const float*)&w4[cc];
                acc[si][0] += ev * wp[0];
                acc[si][1] += ev * wp[1];
                acc[si][2] += ev * wp[2];
                acc[si][3] += ev * wp[3];
            }
        }
    }
#pragma unroll
    for (int si = 0; si < 4; ++si) {
        float4 sv;
        sv.x = acc[si][0]; sv.y = acc[si][1]; sv.z = acc[si][2]; sv.w = acc[si][3];
        *(float4*)&gi[(size_t)(s0 + sb4 + si) * G3 + g0 + ob4] = sv;
    }
}

// ---------------------------------------------------------------------------
// K1c: pre-swizzle hw2_1 into bf16 MFMA B-fragment order.
// ---------------------------------------------------------------------------
__global__ __launch_bounds__(256) void k_prepW(
    const float* __restrict__ W, unsigned short* __restrict__ W_swz)
{
    int fid = blockIdx.x * 256 + threadIdx.x;       // 0..131071 fragment-lane id
    int lane = fid & 63;
    int nt = (fid >> 6) & 3;
    int ks = (fid >> 8) & 3;
    int j  = fid >> 10;
    int col = nt * 16 + (lane & 15);
    int kbase = ks * 32 + ((lane >> 4) * 8);
    const float* src = W + ((size_t)j * 128 + kbase) * 64 + col;
    unsigned short o[8];
#pragma unroll
    for (int i = 0; i < 8; ++i) o[i] = f2bf_rne(src[(size_t)i * 64]);
    *(uint4*)&W_swz[(size_t)fid * 8] = *(const uint4*)o;
}

// ---------------------------------------------------------------------------
// K2: GRU scan, v2 (512 thr, Wh in VGPRs, 2-deep gi prefetch, 1 barrier/step)
// ---------------------------------------------------------------------------
__global__ __launch_bounds__(512, 2) void k_gru(
    const float* __restrict__ gi, const float* __restrict__ Wh, const float* __restrict__ bh,
    const int* __restrict__ dones, const float* __restrict__ h0,
    float* __restrict__ emb_seq, unsigned short* __restrict__ embb,
    float* __restrict__ hid_out)
{
    __shared__ float h_lds[2][144];     // 4 quarters x 36 floats (padded), x2 buffers
    int b = blockIdx.x, tid = threadIdx.x;
    int c = tid >> 2, q = tid & 3;
    int posc = (c >> 5) * 36 + (c & 31);

    float W[96];
#pragma unroll
    for (int g = 0; g < 3; ++g)
#pragma unroll
        for (int i = 0; i < 32; ++i)
            W[g * 32 + i] = Wh[(size_t)(q * 32 + i) * G3 + g * 128 + c];
    float bq0 = bh[c], bq1 = bh[128 + c], bq2 = bh[256 + c];

    if (tid < 128) h_lds[0][(tid >> 5) * 36 + (tid & 31)] = h0[(size_t)b * FC + tid];

    const float* g0p = gi + ((size_t)0 * BB + b) * G3;
    const float* g1p = gi + ((size_t)1 * BB + b) * G3;
    float gc0 = g0p[c], gc1 = g0p[128 + c], gc2 = g0p[256 + c];
    float n10 = g1p[c], n11 = g1p[128 + c], n12 = g1p[256 + c];
    int dval = dones[b];
    int dn1 = dones[BB + b];
    __syncthreads();

    int cur = 0;
    for (int t = 0; t < TT; ++t) {
        int t2 = (t + 2 < TT) ? t + 2 : TT - 1;
        const float* gp2 = gi + ((size_t)t2 * BB + b) * G3;
        float p0 = gp2[c], p1 = gp2[128 + c], p2 = gp2[256 + c];
        int pd = dones[t2 * BB + b];

        float d0 = 0.f, d1 = 0.f, d2 = 0.f;
        const float* hb = &h_lds[cur][q * 36];
#pragma unroll
        for (int i4 = 0; i4 < 8; ++i4) {
            float4 h4 = *(const float4*)&hb[i4 * 4];
            const float* hp = (const float*)&h4;
#pragma unroll
            for (int e = 0; e < 4; ++e) {
                int i = i4 * 4 + e;
                d0 += W[i] * hp[e];
                d1 += W[32 + i] * hp[e];
                d2 += W[64 + i] * hp[e];
            }
        }
        d0 += __shfl_xor(d0, 1, 64); d0 += __shfl_xor(d0, 2, 64);
        d1 += __shfl_xor(d1, 1, 64); d1 += __shfl_xor(d1, 2, 64);
        d2 += __shfl_xor(d2, 1, 64); d2 += __shfl_xor(d2, 2, 64);

        float hs = dval ? 0.0f : 1.0f;
        float hold = h_lds[cur][posc];
        float r = sigmoidf_(gc0 + d0 * hs + bq0);
        float z = sigmoidf_(gc1 + d1 * hs + bq1);
        float n = tanhf_(gc2 + r * (d2 * hs + bq2));
        float hnew = (1.0f - z) * n + z * (hs * hold);

        if (q == 0) {
            h_lds[cur ^ 1][posc] = hnew;
            emb_seq[((size_t)t * BB + b) * FC + c] = hnew;
            embb[((size_t)t * BB + b) * FC + c] = f2bf_rne(hnew);
        }
        gc0 = n10; gc1 = n11; gc2 = n12;
        n10 = p0;  n11 = p1;  n12 = p2;
        dval = dn1; dn1 = pd;
        __syncthreads();
        cur ^= 1;
    }
    if (tid < 128) hid_out[(size_t)b * FC + tid] = h_lds[cur][(tid >> 5) * 36 + (tid & 31)];
}

// ---------------------------------------------------------------------------
// K3: tiny transformer on capability features.
// ---------------------------------------------------------------------------
__global__ __launch_bounds__(256) void k_attn(
    const float* __restrict__ fobs,
    const float* __restrict__ tWq, const float* __restrict__ tWk,
    const float* __restrict__ tWv, const float* __restrict__ tWo,
    const float* __restrict__ ln1s, const float* __restrict__ ln1b,
    const float* __restrict__ ffw1, const float* __restrict__ ffb1,
    const float* __restrict__ ffw2, const float* __restrict__ ffb2,
    const float* __restrict__ ln2s, const float* __restrict__ ln2b,
    float* __restrict__ cap_repr)
{
    __shared__ float wq[2][8][8], wk[2][8][8], wv[2][8][8], wo[2][8][8];
    __shared__ float l1s[2][8], l1b[2][8], l2s[2][8], l2b[2][8];
    __shared__ float f1[2][8][64], fb1[2][64];
    __shared__ float f2[2][64][8], fb2w[2][8];
    __shared__ float k_l[32][8][9], v_l[32][8][9];
    int tid = threadIdx.x;
    for (int i = tid; i < 128; i += 256) {
        ((float*)wq)[i] = tWq[i]; ((float*)wk)[i] = tWk[i];
        ((float*)wv)[i] = tWv[i]; ((float*)wo)[i] = tWo[i];
        ((float*)fb1)[i] = ffb1[i];
    }
    if (tid < 16) {
        ((float*)l1s)[tid] = ln1s[tid]; ((float*)l1b)[tid] = ln1b[tid];
        ((float*)l2s)[tid] = ln2s[tid]; ((float*)l2b)[tid] = ln2b[tid];
        ((float*)fb2w)[tid] = ffb2[tid];
    }
    for (int i = tid; i < 1024; i += 256) { ((float*)f1)[i] = ffw1[i]; ((float*)f2)[i] = ffw2[i]; }
    int sl = tid >> 3, a = tid & 7;
    int s = blockIdx.x * 32 + sl;
    float x[8];
#pragma unroll
    for (int i = 0; i < 7; ++i) x[i] = fobs[(size_t)s * FOBS + OBSD + a * 7 + i];
    x[7] = (a == 0) ? 1.0f : 0.0f;
    __syncthreads();
    for (int l = 0; l < 2; ++l) {
        float q[8], k[8], v[8];
#pragma unroll
        for (int d = 0; d < 8; ++d) { q[d] = 0.f; k[d] = 0.f; v[d] = 0.f; }
#pragma unroll
        for (int e = 0; e < 8; ++e) {
            float xe = x[e];
#pragma unroll
            for (int d = 0; d < 8; ++d) {
                q[d] += xe * wq[l][e][d];
                k[d] += xe * wk[l][e][d];
                v[d] += xe * wv[l][e][d];
            }
        }
#pragma unroll
        for (int d = 0; d < 8; ++d) { k_l[sl][a][d] = k[d]; v_l[sl][a][d] = v[d]; }
        __syncthreads();
        float o[8];
#pragma unroll
        for (int h = 0; h < 4; ++h) {
            float sc[8]; float mx = -1e30f;
#pragma unroll
            for (int ka = 0; ka < 8; ++ka) {
                float sv = (q[2 * h] * k_l[sl][ka][2 * h] + q[2 * h + 1] * k_l[sl][ka][2 * h + 1])
                           * 0.70710678118654752f;
                sc[ka] = sv; mx = fmaxf(mx, sv);
            }
            float ssum = 0.f;
#pragma unroll
            for (int ka = 0; ka < 8; ++ka) { sc[ka] = __expf(sc[ka] - mx); ssum += sc[ka]; }
            float inv = 1.0f / ssum;
            float o0 = 0.f, o1 = 0.f;
#pragma unroll
            for (int ka = 0; ka < 8; ++ka) {
                float at = sc[ka] * inv;
                o0 += at * v_l[sl][ka][2 * h];
                o1 += at * v_l[sl][ka][2 * h + 1];
            }
            o[2 * h] = o0; o[2 * h + 1] = o1;
        }
        float y[8];
#pragma unroll
        for (int e = 0; e < 8; ++e) y[e] = x[e];
#pragma unroll
        for (int d = 0; d < 8; ++d) {
            float od = o[d];
#pragma unroll
            for (int e = 0; e < 8; ++e) y[e] += od * wo[l][d][e];
        }
        {
            float m = 0.f;
#pragma unroll
            for (int e = 0; e < 8; ++e) m += y[e];
            m *= 0.125f;
            float vv = 0.f;
#pragma unroll
            for (int e = 0; e < 8; ++e) { float dd = y[e] - m; vv += dd * dd; }
            vv *= 0.125f;
            float rs = rsqrtf(vv + 1e-6f);
#pragma unroll
            for (int e = 0; e < 8; ++e)
                x[e] = 2.0f * ((y[e] - m) * rs * l1s[l][e] + l1b[l][e]);
        }
        float t1[64];
#pragma unroll
        for (int f = 0; f < 64; ++f) t1[f] = 0.f;
#pragma unroll
        for (int e = 0; e < 8; ++e) {
            float xe = x[e];
#pragma unroll
            for (int f = 0; f < 64; ++f) t1[f] += xe * f1[l][e][f];
        }
        float y2[8];
#pragma unroll
        for (int e = 0; e < 8; ++e) y2[e] = x[e] + fb2w[l][e];   // residual + ffb2
#pragma unroll
        for (int f = 0; f < 64; ++f) {
            float tf = fmaxf(t1[f] + fb1[l][f], 0.0f);
#pragma unroll
            for (int e = 0; e < 8; ++e) y2[e] += tf * f2[l][f][e];
        }
        {
            float m = 0.f;
#pragma unroll
            for (int e = 0; e < 8; ++e) m += y2[e];
            m *= 0.125f;
            float vv = 0.f;
#pragma unroll
            for (int e = 0; e < 8; ++e) { float dd = y2[e] - m; vv += dd * dd; }
            vv *= 0.125f;
            float rs = rsqrtf(vv + 1e-6f);
#pragma unroll
            for (int e = 0; e < 8; ++e)
                x[e] = 2.0f * ((y2[e] - m) * rs * l2s[l][e] + l2b[l][e]);
        }
        __syncthreads();
    }
#pragma unroll
    for (int e = 0; e < 8; ++e) {
        float xv = x[e];
        xv += __shfl_xor(xv, 1, 8);
        xv += __shfl_xor(xv, 2, 8);
        xv += __shfl_xor(xv, 4, 8);
        if (a == 0) cap_repr[(size_t)s * 8 + e] = xv * 0.125f;
    }
}

// ---------------------------------------------------------------------------
// K3b: hypernet first layers + small second layers.
// ---------------------------------------------------------------------------
__global__ __launch_bounds__(256) void k_hyper(
    const float* __restrict__ cap_repr, const float* __restrict__ emb_seq,
    const float* __restrict__ hw1_1, const float* __restrict__ hb1_1,
    const float* __restrict__ hw1_2, const float* __restrict__ hb1_2,
    const float* __restrict__ hw1_3, const float* __restrict__ hb1_3,
    const float* __restrict__ hw1_4, const float* __restrict__ hb1_4,
    const float* __restrict__ hb2_1,
    const float* __restrict__ hw2_2, const float* __restrict__ hb2_2,
    const float* __restrict__ hw2_3, const float* __restrict__ hb2_3,
    const float* __restrict__ hw2_4, const float* __restrict__ hb2_4,
    float* __restrict__ hh1g, float* __restrict__ b1eff,
    float* __restrict__ w2h, float* __restrict__ b2h)
{
    __shared__ float cr[16][8];
    __shared__ float hh[4][16][132];
    __shared__ float es[16][132];
    int tid = threadIdx.x;
    int s0 = blockIdx.x * 16;
    if (tid < 128) ((float*)cr)[tid] = cap_repr[(size_t)s0 * 8 + tid];
#pragma unroll
    for (int i = 0; i < 2; ++i) {
        int idx = tid + i * 256;
        int r = idx >> 5, c4 = idx & 31;
        float4 v = *(const float4*)&emb_seq[(size_t)(s0 + r) * FC + c4 * 4];
        *(float4*)&es[r][c4 * 4] = v;
    }
    __syncthreads();
#pragma unroll
    for (int it = 0; it < 32; ++it) {
        int idx = tid + it * 256;
        int u = idx & 127;
        int sn = (idx >> 7) & 15;
        int n = idx >> 11;
        const float* w = (n == 0) ? hw1_1 : ((n == 1) ? hw1_2 : ((n == 2) ? hw1_3 : hw1_4));
        const float* bb = (n == 0) ? hb1_1 : ((n == 1) ? hb1_2 : ((n == 2) ? hb1_3 : hb1_4));
        float acc = bb[u];
#pragma unroll
        for (int e = 0; e < 8; ++e) acc += cr[sn][e] * w[e * 128 + u];
        acc = fmaxf(acc, 0.0f);
        hh[n][sn][u] = acc;
        if (n == 0) hh1g[(size_t)(s0 + sn) * 128 + u] = acc;
    }
    __syncthreads();
#pragma unroll
    for (int it = 0; it < 4; ++it) {
        int idx = tid + it * 256;
        int o = idx & 63, sn = idx >> 6;
        float acc = hb2_2[o];
        for (int j = 0; j < 128; ++j) acc += hh[1][sn][j] * hw2_2[j * 64 + o];
        for (int c = 0; c < 128; ++c) acc += es[sn][c] * hb2_1[c * 64 + o];
        b1eff[(size_t)(s0 + sn) * 64 + o] = acc;
    }
    for (int it = 0; it < 2; ++it) {
        int oa = tid + it * 256;
        if (oa < 320) {
            float acc[16];
#pragma unroll
            for (int sn = 0; sn < 16; ++sn) acc[sn] = 0.f;
            for (int j = 0; j < 128; ++j) {
                float w = hw2_3[j * 320 + oa];
#pragma unroll
                for (int sn = 0; sn < 16; ++sn) acc[sn] += hh[2][sn][j] * w;
            }
            float bb = hb2_3[oa];
#pragma unroll
            for (int sn = 0; sn < 16; ++sn) w2h[(size_t)(s0 + sn) * 320 + oa] = acc[sn] + bb;
        }
    }
    if (tid < 80) {
        int aa = tid % 5, sn = tid / 5;
        float acc = hb2_4[aa];
        for (int j = 0; j < 128; ++j) acc += hh[3][sn][j] * hw2_4[j * 5 + aa];
        b2h[(size_t)(s0 + sn) * 5 + aa] = acc;
    }
}

// ---------------------------------------------------------------------------
// K4: big GEMM via bf16 MFMA, v2: double-buffered LDS (1 barrier/j) +
// 2-deep global prefetch (LDS write consumes loads issued a full j earlier).
// ---------------------------------------------------------------------------
__global__ __launch_bounds__(256) void k_bigmm_mfma(
    const unsigned short* __restrict__ embb, const float* __restrict__ hh1g,
    const unsigned short* __restrict__ W_swz, float* __restrict__ partials)
{
    __shared__ uint4 w_lds[2][1024];       // 2 x 16 KB double buffer
    __shared__ float hh1_lds[64][33];      // 8.45 KB
    int tid = threadIdx.x;
    int w = tid >> 6, lane = tid & 63;
    int mt = blockIdx.x >> 2, ksp = blockIdx.x & 3;
    int s0 = mt * 64, j0 = ksp * 32;

    // stage hh1 tile (rows s0..+64, j-range j0..+32)
#pragma unroll
    for (int it = 0; it < 8; ++it) {
        int idx = tid + it * 256;
        int r = idx >> 5, jj = idx & 31;
        hh1_lds[r][jj] = hh1g[(size_t)(s0 + r) * 128 + j0 + jj];
    }

    // pin this lane's emb bf16 A-fragments: 2 row-tiles x 4 k-steps x 8 bf16
    bf16x8 emb_r[2][4];
    int rbase = s0 + (w >> 1) * 32 + (lane & 15);
    int cbase = (lane >> 4) * 8;
#pragma unroll
    for (int rt = 0; rt < 2; ++rt)
#pragma unroll
        for (int ks = 0; ks < 4; ++ks)
            emb_r[rt][ks] = *(const bf16x8*)&embb[(size_t)(rbase + rt * 16) * 128 + ks * 32 + cbase];

    const uint4* Wg = (const uint4*)W_swz;   // 1024 uint4 per j
    uint4 wreg[4];
    // prologue: fill buf0 with j0; prefetch j0+1 into wreg
#pragma unroll
    for (int q = 0; q < 4; ++q) wreg[q] = Wg[(size_t)j0 * 1024 + q * 256 + tid];
#pragma unroll
    for (int q = 0; q < 4; ++q) w_lds[0][q * 256 + tid] = wreg[q];
#pragma unroll
    for (int q = 0; q < 4; ++q) wreg[q] = Wg[(size_t)(j0 + 1) * 1024 + q * 256 + tid];

    int nt0 = (w & 1) * 2;
    f32x4 acc[2][2];
#pragma unroll
    for (int a = 0; a < 2; ++a)
#pragma unroll
        for (int b = 0; b < 2; ++b) acc[a][b] = (f32x4){0.f, 0.f, 0.f, 0.f};

    int rl0 = (w >> 1) * 32 + 4 * (lane >> 4);   // hh1_lds row base
    __syncthreads();   // hh1 + buf0 ready

    for (int jj = 0; jj < 32; ++jj) {
        int p = jj & 1;
        // write buffer for j+1 (regs loaded one full iteration ago), then
        // issue loads for j+2 — both overlap the compute below.
        if (jj < 31) {
#pragma unroll
            for (int q = 0; q < 4; ++q) w_lds[p ^ 1][q * 256 + tid] = wreg[q];
            if (jj < 30) {
#pragma unroll
                for (int q = 0; q < 4; ++q)
                    wreg[q] = Wg[(size_t)(j0 + jj + 2) * 1024 + q * 256 + tid];
            }
        }
        // P_j = emb @ B_j   (pure MFMA chain, P init 0)
        f32x4 P00 = (f32x4){0.f, 0.f, 0.f, 0.f};
        f32x4 P01 = (f32x4){0.f, 0.f, 0.f, 0.f};
        f32x4 P10 = (f32x4){0.f, 0.f, 0.f, 0.f};
        f32x4 P11 = (f32x4){0.f, 0.f, 0.f, 0.f};
#pragma unroll
        for (int ks = 0; ks < 4; ++ks) {
            bf16x8 b0 = *(const bf16x8*)&w_lds[p][(ks * 4 + nt0) * 64 + lane];
            bf16x8 b1 = *(const bf16x8*)&w_lds[p][(ks * 4 + nt0 + 1) * 64 + lane];
            P00 = __builtin_amdgcn_mfma_f32_16x16x32_bf16(emb_r[0][ks], b0, P00, 0, 0, 0);
            P01 = __builtin_amdgcn_mfma_f32_16x16x32_bf16(emb_r[0][ks], b1, P01, 0, 0, 0);
            P10 = __builtin_amdgcn_mfma_f32_16x16x32_bf16(emb_r[1][ks], b0, P10, 0, 0, 0);
            P11 = __builtin_amdgcn_mfma_f32_16x16x32_bf16(emb_r[1][ks], b1, P11, 0, 0, 0);
        }
        // fold h: acc[rt][nt][r] += h[row(rt,r)] * P[rt][nt][r]
#pragma unroll
        for (int r = 0; r < 4; ++r) {
            float h0 = hh1_lds[rl0 + r][jj];
            float h1 = hh1_lds[rl0 + 16 + r][jj];
            acc[0][0][r] += h0 * P00[r];
            acc[0][1][r] += h0 * P01[r];
            acc[1][0][r] += h1 * P10[r];
            acc[1][1][r] += h1 * P11[r];
        }
        __syncthreads();   // single barrier: buf[p] reads done, buf[p^1] writes visible
    }
    // epilogue: D layout col=lane&15, row=4*(lane>>4)+r (m89-verified)
    float* pb = partials + (size_t)ksp * (NS * 64);
#pragma unroll
    for (int rt = 0; rt < 2; ++rt) {
#pragma unroll
        for (int n = 0; n < 2; ++n) {
            int colg = (w & 1) * 32 + n * 16 + (lane & 15);
#pragma unroll
            for (int r = 0; r < 4; ++r) {
                int rowg = s0 + (w >> 1) * 32 + rt * 16 + 4 * (lane >> 4) + r;
                pb[(size_t)rowg * 64 + colg] = acc[rt][n][r];
            }
        }
    }
}

// ---------------------------------------------------------------------------
// K5: epilogue. h1 = relu(sum_k partials + b1eff); logits = h1@w2 + b2.
// ---------------------------------------------------------------------------
__global__ __launch_bounds__(256) void k_final(
    const float* __restrict__ partials, const float* __restrict__ b1eff,
    const float* __restrict__ w2h, const float* __restrict__ b2h, float* __restrict__ out)
{
    int tid = threadIdx.x;
    int wv = tid >> 6, lane = tid & 63;
    int s = blockIdx.x * 4 + wv;
    float h1 = b1eff[(size_t)s * 64 + lane];
#pragma unroll
    for (int ks = 0; ks < 4; ++ks) h1 += partials[(size_t)ks * (NS * 64) + (size_t)s * 64 + lane];
    h1 = fmaxf(h1, 0.0f);
    float lg[5];
#pragma unroll
    for (int aa = 0; aa < 5; ++aa) lg[aa] = h1 * w2h[(size_t)s * 320 + lane * 5 + aa];
#pragma unroll
    for (int off = 32; off >= 1; off >>= 1) {
#pragma unroll
        for (int aa = 0; aa < 5; ++aa) lg[aa] += __shfl_xor(lg[aa], off, 64);
    }
    if (lane == 0) {
#pragma unroll
        for (int aa = 0; aa < 5; ++aa)
            out[16384 + (size_t)s * 5 + aa] = lg[aa] + b2h[(size_t)s * 5 + aa];
    }
}

// ---------------------------------------------------------------------------
extern "C" void kernel_launch(void* const* d_in, const int* in_sizes, int n_in,
                              void* d_out, int out_size, void* d_ws, size_t ws_size,
                              hipStream_t stream)
{
    (void)in_sizes; (void)n_in; (void)out_size; (void)ws_size;
    const float* hidden  = (const float*)d_in[0];
    const float* fobs    = (const float*)d_in[1];
    const int*   dones   = (const int*)d_in[2];
    const float* embed_w = (const float*)d_in[3];
    const float* embed_b = (const float*)d_in[4];
    const float* gru_wi  = (const float*)d_in[5];
    const float* gru_wh  = (const float*)d_in[6];
    const float* gru_bh  = (const float*)d_in[7];
    const float* tWq  = (const float*)d_in[8];
    const float* tWk  = (const float*)d_in[9];
    const float* tWv  = (const float*)d_in[10];
    const float* tWo  = (const float*)d_in[11];
    const float* ln1s = (const float*)d_in[12];
    const float* ln1b = (const float*)d_in[13];
    const float* ffw1 = (const float*)d_in[14];
    const float* ffb1 = (const float*)d_in[15];
    const float* ffw2 = (const float*)d_in[16];
    const float* ffb2 = (const float*)d_in[17];
    const float* ln2s = (const float*)d_in[18];
    const float* ln2b = (const float*)d_in[19];
    const float* hw1_1 = (const float*)d_in[20]; const float* hb1_1 = (const float*)d_in[21];
    const float* hw2_1 = (const float*)d_in[22]; const float* hb2_1 = (const float*)d_in[23];
    const float* hw1_2 = (const float*)d_in[24]; const float* hb1_2 = (const float*)d_in[25];
    const float* hw2_2 = (const float*)d_in[26]; const float* hb2_2 = (const float*)d_in[27];
    const float* hw1_3 = (const float*)d_in[28]; const float* hb1_3 = (const float*)d_in[29];
    const float* hw2_3 = (const float*)d_in[30]; const float* hb2_3 = (const float*)d_in[31];
    const float* hw1_4 = (const float*)d_in[32]; const float* hb1_4 = (const float*)d_in[33];
    const float* hw2_4 = (const float*)d_in[34]; const float* hb2_4 = (const float*)d_in[35];
    float* out = (float*)d_out;
    float* ws  = (float*)d_ws;

    // workspace layout (floats). Overlays:
    //  - parts (8 MB) aliases gi (12 MB, dead after k_gru)
    //  - W_swz (2 MB) + emb_bf16 (2 MB) alias emb (4 MB, dead after k_gi)
    float* gi      = ws;                      // 8192*384
    float* parts   = ws;                      // 4*8192*64 (aliases gi)
    float* emb     = gi      + 3145728;       // 8192*128 (dead after k_gi)
    unsigned short* W_swz    = (unsigned short*)emb;              // 1M bf16 = 2 MB
    unsigned short* emb_bf16 = (unsigned short*)(emb + 524288);   // 1M bf16 = 2 MB
    float* emb_seq = emb     + 1048576;       // 8192*128
    float* cap_rep = emb_seq + 1048576;       // 8192*8
    float* hh1g    = cap_rep + 65536;         // 8192*128
    float* b1eff_  = hh1g    + 1048576;       // 8192*64
    float* w2hb    = b1eff_  + 524288;        // 8192*320
    float* b2hb    = w2hb    + 2621440;       // 8192*5

    k_embed<<<128, 256, 0, stream>>>(fobs, embed_w, embed_b, emb);
    k_gi<<<768, 256, 0, stream>>>(emb, gru_wi, gi);
    k_prepW<<<512, 256, 0, stream>>>(hw2_1, W_swz);
    k_gru<<<128, 512, 0, stream>>>(gi, gru_wh, gru_bh, dones, hidden, emb_seq, emb_bf16, out);
    k_attn<<<256, 256, 0, stream>>>(fobs, tWq, tWk, tWv, tWo, ln1s, ln1b,
                                    ffw1, ffb1, ffw2, ffb2, ln2s, ln2b, cap_rep);
    k_hyper<<<512, 256, 0, stream>>>(cap_rep, emb_seq,
                                     hw1_1, hb1_1, hw1_2, hb1_2, hw1_3, hb1_3, hw1_4, hb1_4,
                                     hb2_1, hw2_2, hb2_2, hw2_3, hb2_3, hw2_4, hb2_4,
                                     hh1g, b1eff_, w2hb, b2hb);
    k_bigmm_mfma<<<512, 256, 0, stream>>>(emb_bf16, hh1g, W_swz, parts);
    k_final<<<2048, 256, 0, stream>>>(parts, b1eff_, w2hb, b2hb, out);
}